// Round 1
// baseline (395.768 us; speedup 1.0000x reference)
//
#include <hip/hip_runtime.h>
#include <hip/hip_bf16.h>

// NodeSAGELSTM: 2x SAGEConv(project=True, mean aggr) + ReLU, then LSTM(proj=3).
//
// R16 (from R15 @ 371.9us; lstm_chunk_k = 61.5us, VALUBusy 51%, Occ 12%):
//  - LSTM rebuilt as 2-chains-per-wave + depth-3 rotating ring prefetch.
//    Theory: at ~1 wave/SIMD the serial recurrence (~150cy dep chain/step)
//    plus a ~1-step (~290cy) effective load lead (the old p=pn shift consumed
//    the newest load in the same step) left the SIMD stalled half the time.
//    Two independent chunks interleaved in one wave double issue density
//    (~580cy/step) and the ring (use slot t%3, reload freed slot with row
//    t+3) gives a ~1700cy load->use distance, covering HBM-miss latency.
//  - Chunk 0 handled uniformly: burns on clamped row-0 reads, state reset to
//    zero before the write phase (recurrence bitwise identical to R15).
//  - Grid 2000 -> 1000 blocks; weights shared across the 2 chains.
//  Everything else identical to R15.

#define NN 50000
#define NE 600000
#define CHUNKS 2000
#define CLEN 25
#define BURN 16

typedef __attribute__((ext_vector_type(8))) short bf16x8;
typedef __attribute__((ext_vector_type(4))) float f32x4;

__device__ __forceinline__ float bf2f(unsigned short u) {
    union { unsigned int i; float f; } v; v.i = ((unsigned int)u) << 16; return v.f;
}
__device__ __forceinline__ unsigned short f2bf(float f) {
    union { float f; unsigned int i; } v; v.f = f;
    unsigned int x = v.i;
    return (unsigned short)((x + 0x7FFFu + ((x >> 16) & 1u)) >> 16);
}
__device__ __forceinline__ float sigm(float x) { return 1.f / (1.f + __expf(-x)); }
__device__ __forceinline__ float tanh_(float x) {
    float t = __expf(2.f * x);          // saturates cleanly at +-1
    return 1.f - 2.f / (t + 1.f);
}

// Self-detection (uniform, branch-free, L1-cached probes).
__device__ __forceinline__ bool detect_fp32(const unsigned int* __restrict__ xw) {
    int cnt = 0;
#pragma unroll
    for (int i = 0; i < 32; ++i) {
        float av = fabsf(bf2f((unsigned short)(xw[i] & 0xFFFFu)));
        cnt += (av > 1e-6f && av < 1e4f) ? 1 : 0;
    }
    return cnt < 16;
}
__device__ __forceinline__ bool detect_is64(const int* __restrict__ ei) {
    bool z = true;
#pragma unroll
    for (int i = 1; i < 16; i += 2) z = z && (ei[i] == 0);
    return z;
}

// 64-lane sum via DPP (row_shr 1/2/4/8 + row_bcast 15/31); result in lane 63.
__device__ __forceinline__ float dpp_sum64(float x) {
    int v;
    v = __builtin_amdgcn_update_dpp(0, __float_as_int(x), 0x111, 0xf, 0xf, true);
    x += __int_as_float(v);
    v = __builtin_amdgcn_update_dpp(0, __float_as_int(x), 0x112, 0xf, 0xf, true);
    x += __int_as_float(v);
    v = __builtin_amdgcn_update_dpp(0, __float_as_int(x), 0x114, 0xf, 0xf, true);
    x += __int_as_float(v);
    v = __builtin_amdgcn_update_dpp(0, __float_as_int(x), 0x118, 0xf, 0xf, true);
    x += __int_as_float(v);
    v = __builtin_amdgcn_update_dpp(0, __float_as_int(x), 0x142, 0xa, 0xf, true);
    x += __int_as_float(v);
    v = __builtin_amdgcn_update_dpp(0, __float_as_int(x), 0x143, 0xc, 0xf, true);
    x += __int_as_float(v);
    return x;
}
__device__ __forceinline__ float lane63(float x) {
    return __int_as_float(__builtin_amdgcn_readlane(__float_as_int(x), 63));
}

__device__ __forceinline__ int clampn(int v) {
    v = v < 0 ? 0 : v; return v >= NN ? NN - 1 : v;
}
__device__ __forceinline__ int edst(const int* ei, int e, bool is64) {
    return clampn(is64 ? ei[2 * NE + 2 * e] : ei[NE + e]);
}
__device__ __forceinline__ int esrc(const int* ei, int e, bool is64) {
    return clampn(is64 ? ei[2 * e] : ei[e]);
}

// ---- weight conversion (device body; called from fused K1) ----
struct WSrc { const void* p[15]; };
__device__ __forceinline__ void cvt_w_body(
    const WSrc& sp, unsigned short* __restrict__ wbuf, bool f32,
    int seg, int i)
{
    static const int segoff[15] = {0, 16384, 16512, 32896, 33024, 49408, 65792,
                                   65920, 82304, 82432, 98816, 164352, 165888,
                                   166400, 166912};
    static const int segn[15]   = {16384, 128, 16384, 128, 16384, 16384, 128,
                                   16384, 128, 16384, 65536, 1536, 512, 512, 384};
    static const int segmat[15] = {1, 0, 1, 0, 1, 1, 0, 1, 0, 1, 1, 0, 0, 0, 0};
    if (i >= segn[seg]) return;
    float val;
    if (f32) val = ((const float*)sp.p[seg])[i];
    else     val = bf2f(((const unsigned short*)sp.p[seg])[i]);
    int dst = i;
    if (segmat[seg]) {
        int row = i >> 7, kcol = i & 127;
        int tile = row >> 7, r = row & 127;
        int c = r >> 4, m = r & 15;
        int ks = kcol >> 5, kh = (kcol >> 3) & 3, j = kcol & 7;
        dst = (tile << 14) + (((c << 8) + (ks << 6) + (kh << 4) + m) << 3) + j;
    }
    wbuf[segoff[seg] + dst] = f2bf(val);
}

#define HISTB 2344   // ceil(600000/256)

// K1: hist (blocks [0,HISTB)) || weight convert (blocks [HISTB, HISTB+3840))
__global__ __launch_bounds__(256) void k1_hist_cvtw(
    const int* __restrict__ ei, int* __restrict__ hist,
    WSrc sp, unsigned short* __restrict__ wbuf,
    const unsigned int* __restrict__ xprobe)
{
    int bid = blockIdx.x;
    if (bid < HISTB) {
        bool is64 = detect_is64(ei);
        int e = bid * 256 + threadIdx.x;
        if (e < NE) atomicAdd(hist + edst(ei, e, is64), 1);
    } else {
        int b2 = bid - HISTB;
        int seg = b2 >> 8;
        int i = (b2 & 255) * 256 + threadIdx.x;
        bool f32 = detect_fp32(xprobe);
        cvt_w_body(sp, wbuf, f32, seg, i);
    }
}

#define STILES 49   // ceil(50000/1024)

__global__ __launch_bounds__(1024) void scanA_k(
    const int* __restrict__ hist, int* __restrict__ offs, int* __restrict__ tsum)
{
    __shared__ int sh[1024];
    int t = threadIdx.x, idx = blockIdx.x * 1024 + t;
    int v = (idx < NN) ? hist[idx] : 0;
    sh[t] = v;
    __syncthreads();
    int acc = v;
    for (int off = 1; off < 1024; off <<= 1) {
        int y = (t >= off) ? sh[t - off] : 0;
        __syncthreads();
        acc += y; sh[t] = acc;
        __syncthreads();
    }
    if (idx < NN) offs[idx] = acc - v;            // exclusive within tile
    if (t == 1023) tsum[blockIdx.x] = acc;        // tile total
}

__global__ __launch_bounds__(1024) void scanC_k(
    int* __restrict__ offs, int* __restrict__ cursor, const int* __restrict__ tsum)
{
    __shared__ int sbase;
    int t = threadIdx.x;
    if (t < 64) {
        int v = (t < STILES && t < (int)blockIdx.x) ? tsum[t] : 0;
#pragma unroll
        for (int off = 32; off > 0; off >>= 1) v += __shfl_xor(v, off, 64);
        if (t == 0) sbase = v;
    }
    __syncthreads();
    int idx = blockIdx.x * 1024 + t;
    if (idx < NN) {
        int o = offs[idx] + sbase;
        offs[idx] = o; cursor[idx] = o;
    }
    if (blockIdx.x == STILES - 1 && t == 0) offs[NN] = NE;
}

// A-fragment load: bf16x8 from bf16 buffer, or inline-convert from fp32 input.
__device__ __forceinline__ bf16x8 load_a8(const void* A, size_t off, bool f32) {
    if (f32) {
        const float* pf = (const float*)A + off;
        f32x4 u0 = *(const f32x4*)pf;
        f32x4 u1 = *(const f32x4*)(pf + 4);
        bf16x8 r;
        r[0] = (short)f2bf(u0[0]); r[1] = (short)f2bf(u0[1]);
        r[2] = (short)f2bf(u0[2]); r[3] = (short)f2bf(u0[3]);
        r[4] = (short)f2bf(u1[0]); r[5] = (short)f2bf(u1[1]);
        r[6] = (short)f2bf(u1[2]); r[7] = (short)f2bf(u1[3]);
        return r;
    }
    return *(const bf16x8*)((const unsigned short*)A + off);
}

// GEMM body (R11 structure): W/W2 in fragment order, staged to LDS (flat int4
// copy); B-fragments via conflict-free contiguous ds_read_b128; A-loads
// hoisted above the staging barrier.
__device__ __forceinline__ void gemm_body(
    char* smem, int bidx, int cb,
    const void* __restrict__ A, const void* __restrict__ A2,
    const unsigned short* __restrict__ W, const unsigned short* __restrict__ W2,
    const unsigned short* __restrict__ b1, const unsigned short* __restrict__ b2,
    unsigned short* __restrict__ out,
    int n_rows, int relu_flag, int out_stride, bool af32, bool a2f32)
{
    const int tid  = threadIdx.x;
    const int lane = tid & 63;
    const int wv   = tid >> 6;
    const int row0 = bidx * 64 + wv * 16;
    const int m    = lane & 15;
    const int kh   = lane >> 4;

    int arow = row0 + m; if (arow >= n_rows) arow = n_rows - 1;
    const size_t aoff = (size_t)arow * 128 + kh * 8;

    bf16x8 a[4], a2v[4];
#pragma unroll
    for (int ks = 0; ks < 4; ++ks) a[ks] = load_a8(A, aoff + ks * 32, af32);
    if (A2) {
#pragma unroll
        for (int ks = 0; ks < 4; ++ks) a2v[ks] = load_a8(A2, aoff + ks * 32, a2f32);
    }

    {
        const unsigned short* wt = W + (size_t)cb * 16384;
        int4 tmp[8];
#pragma unroll
        for (int q = 0; q < 8; ++q)
            tmp[q] = *(const int4*)(wt + (size_t)(tid + q * 256) * 8);
#pragma unroll
        for (int q = 0; q < 8; ++q)
            *(int4*)(smem + (size_t)(tid + q * 256) * 16) = tmp[q];
        if (W2) {
            const unsigned short* w2t = W2 + (size_t)cb * 16384;
            int4 tm2[8];
#pragma unroll
            for (int q = 0; q < 8; ++q)
                tm2[q] = *(const int4*)(w2t + (size_t)(tid + q * 256) * 8);
#pragma unroll
            for (int q = 0; q < 8; ++q)
                *(int4*)(smem + 32768 + (size_t)(tid + q * 256) * 16) = tm2[q];
        }
    }
    __syncthreads();

    f32x4 acc[8];
#pragma unroll
    for (int c = 0; c < 8; ++c) acc[c] = (f32x4){0.f, 0.f, 0.f, 0.f};

#pragma unroll
    for (int ks = 0; ks < 4; ++ks) {
#pragma unroll
        for (int c = 0; c < 8; ++c) {
            bf16x8 b = *(const bf16x8*)(smem + (size_t)(c * 256 + ks * 64 + lane) * 16);
            acc[c] = __builtin_amdgcn_mfma_f32_16x16x32_bf16(a[ks], b, acc[c], 0, 0, 0);
        }
        if (W2) {
#pragma unroll
            for (int c = 0; c < 8; ++c) {
                bf16x8 b2 = *(const bf16x8*)(smem + 32768 +
                                             (size_t)(c * 256 + ks * 64 + lane) * 16);
                acc[c] = __builtin_amdgcn_mfma_f32_16x16x32_bf16(a2v[ks], b2, acc[c], 0, 0, 0);
            }
        }
    }

#pragma unroll
    for (int c = 0; c < 8; ++c) {
        int col = cb * 128 + c * 16 + m;    // C/D: col = lane&15
        float bias = 0.f;
        if (b1) bias += bf2f(b1[col]);
        if (b2) bias += bf2f(b2[col]);
#pragma unroll
        for (int r = 0; r < 4; ++r) {
            int row = row0 + kh * 4 + r;    // C/D: row = (lane>>4)*4 + reg
            if (row >= n_rows) continue;
            float v = acc[c][r] + bias;
            if (relu_flag && v < 0.f) v = 0.f;
            out[(size_t)row * out_stride + col] = f2bf(v);
        }
    }
}

__global__ __launch_bounds__(256) void gemm_k128(
    const void* __restrict__ A,
    const void* __restrict__ A2,
    const unsigned short* __restrict__ W,
    const unsigned short* __restrict__ W2,
    const unsigned short* __restrict__ b1,
    const unsigned short* __restrict__ b2,
    unsigned short* __restrict__ out,
    int n_rows, int relu_flag, int out_stride,
    const unsigned int* __restrict__ xprobe, int a_sel, int a2_sel)
{
    extern __shared__ __align__(16) char smem[];
    bool f32 = (a_sel | a2_sel) ? detect_fp32(xprobe) : false;
    gemm_body(smem, blockIdx.x, blockIdx.y, A, A2, W, W2, b1, b2, out,
              n_rows, relu_flag, out_stride, a_sel && f32, a2_sel && f32);
}

// K4: fill (blocks [0,HISTB)) || xp1-GEMM (blocks [HISTB, HISTB+782))
__global__ __launch_bounds__(256) void k4_fill_gemm(
    const int* __restrict__ ei, int* __restrict__ cursor, int* __restrict__ elist,
    const void* __restrict__ x,
    const unsigned short* __restrict__ Wp1, const unsigned short* __restrict__ bp1,
    unsigned short* __restrict__ bufA)
{
    extern __shared__ __align__(16) char smem[];
    int bid = blockIdx.x;
    if (bid < HISTB) {
        bool is64 = detect_is64(ei);
        int e = bid * 256 + threadIdx.x;
        if (e >= NE) return;
        int p = atomicAdd(cursor + edst(ei, e, is64), 1);
        elist[p] = esrc(ei, e, is64);
    } else {
        bool f32 = detect_fp32((const unsigned int*)x);
        gemm_body(smem, bid - HISTB, 0, x, nullptr, Wp1, nullptr, bp1, nullptr,
                  bufA, NN, 1, 128, f32, false);
    }
}

// One wave per node: mean over incoming src rows of xp (bf16), write bf16.
__global__ __launch_bounds__(256) void gather_mean_k(
    const int* __restrict__ offs, const int* __restrict__ elist,
    const unsigned short* __restrict__ xp, unsigned short* __restrict__ out)
{
    const int node = blockIdx.x * 4 + (threadIdx.x >> 6);
    const int lane = threadIdx.x & 63;
    if (node >= NN) return;
    const int beg = offs[node], end = offs[node + 1];
    float a0 = 0.f, a1 = 0.f;
    int e = beg;
    for (; e + 4 <= end; e += 4) {
        int s0 = elist[e], s1 = elist[e + 1], s2 = elist[e + 2], s3 = elist[e + 3];
        unsigned int w0 = *(const unsigned int*)(xp + (size_t)s0 * 128 + lane * 2);
        unsigned int w1 = *(const unsigned int*)(xp + (size_t)s1 * 128 + lane * 2);
        unsigned int w2 = *(const unsigned int*)(xp + (size_t)s2 * 128 + lane * 2);
        unsigned int w3 = *(const unsigned int*)(xp + (size_t)s3 * 128 + lane * 2);
        a0 += bf2f((unsigned short)(w0 & 0xFFFFu)) + bf2f((unsigned short)(w1 & 0xFFFFu))
            + bf2f((unsigned short)(w2 & 0xFFFFu)) + bf2f((unsigned short)(w3 & 0xFFFFu));
        a1 += bf2f((unsigned short)(w0 >> 16)) + bf2f((unsigned short)(w1 >> 16))
            + bf2f((unsigned short)(w2 >> 16)) + bf2f((unsigned short)(w3 >> 16));
    }
    for (; e < end; ++e) {
        int s = elist[e];
        unsigned int w = *(const unsigned int*)(xp + (size_t)s * 128 + lane * 2);
        a0 += bf2f((unsigned short)(w & 0xFFFFu));
        a1 += bf2f((unsigned short)(w >> 16));
    }
    int cnt = end - beg;
    float inv = 1.f / (float)(cnt > 1 ? cnt : 1);
    unsigned int o = (unsigned int)f2bf(a0 * inv) | ((unsigned int)f2bf(a1 * inv) << 16);
    *(unsigned int*)(out + (size_t)node * 128 + lane * 2) = o;
}

// LSTM R16: 2 chains per wave (chunks bid and bid+1000), depth-3 rotating
// ring prefetch (slot t%3 used at step t, reloaded with row t+3 after use --
// no shift-register consuming the newest load). Lane l owns channels
// (2l,2l+1) of each chain; whh/whr shared across chains.
// Chunk 0 (exact, no burn semantics): its chain burns on row-clamped reads
// and state is zeroed before the write phase.
// Prefetch overrun (chain B of bid 999) reads rows NN..NN+2 -> bufA region,
// valid mapped ws memory, values never consumed.
__global__ __launch_bounds__(64) void lstm_chunk_k(
    const unsigned short* __restrict__ pre,
    const unsigned short* __restrict__ Whh,   // [512,3] bf16
    const unsigned short* __restrict__ Whr,   // [3,128] bf16
    void* __restrict__ outv,                  // d_out: hs[150000], hN[3], cN[128]
    const unsigned int* __restrict__ xprobe)
{
    const int bid = blockIdx.x;
    const int lane = threadIdx.x;
    const bool fp32out = detect_fp32(xprobe);
    float* outf = (float*)outv;
    unsigned short* outb = (unsigned short*)outv;
    const int ch0 = 2 * lane;

    float whh[2][4][3];
#pragma unroll
    for (int j = 0; j < 2; ++j)
#pragma unroll
        for (int g = 0; g < 4; ++g)
#pragma unroll
            for (int k = 0; k < 3; ++k)
                whh[j][g][k] = bf2f(Whh[(g * 128 + ch0 + j) * 3 + k]);
    float whr[2][3];
#pragma unroll
    for (int j = 0; j < 2; ++j)
#pragma unroll
        for (int k = 0; k < 3; ++k)
            whr[j][k] = bf2f(Whr[k * 128 + ch0 + j]);

    const int t0q[2] = { bid * CLEN, (bid + CHUNKS / 2) * CLEN };

    float ring[2][3][2][4];
    float h[2][3] = {{0.f, 0.f, 0.f}, {0.f, 0.f, 0.f}};
    float c[2][2] = {{0.f, 0.f}, {0.f, 0.f}};
    int trow[2];
    int T[2] = { t0q[0], t0q[1] };

// Load row r (clamped at 0 for chunk-0's fake burn) into a [2][4] slot.
#define LOADR(dst, r)                                                          \
    {                                                                          \
        const unsigned short* _pp = pre + ((size_t)((r) > 0 ? (r) : 0) << 9);  \
        _Pragma("unroll")                                                      \
        for (int g = 0; g < 4; ++g) {                                          \
            unsigned int w = *(const unsigned int*)(_pp + g * 128 + ch0);      \
            dst[0][g] = bf2f((unsigned short)(w & 0xFFFFu));                   \
            dst[1][g] = bf2f((unsigned short)(w >> 16));                       \
        }                                                                      \
    }

#pragma unroll
    for (int q = 0; q < 2; ++q) {
        int ts = t0q[q] - BURN;            // bid 0, q 0: -16 (clamped reads)
        LOADR(ring[q][0], ts)
        LOADR(ring[q][1], ts + 1)
        LOADR(ring[q][2], ts + 2)
        trow[q] = ts + 3;
    }

// One LSTM step for both chains: use ring slot S, then reload S with row
// trow (consumed 3 steps later).
#define STEP(S, DOW)                                                           \
    {                                                                          \
        _Pragma("unroll")                                                      \
        for (int q = 0; q < 2; ++q) {                                          \
            float gv0[4], gv1[4];                                              \
            _Pragma("unroll")                                                  \
            for (int g = 0; g < 4; ++g) {                                      \
                gv0[g] = ring[q][S][0][g] + whh[0][g][0] * h[q][0]             \
                       + whh[0][g][1] * h[q][1] + whh[0][g][2] * h[q][2];      \
                gv1[g] = ring[q][S][1][g] + whh[1][g][0] * h[q][0]             \
                       + whh[1][g][1] * h[q][1] + whh[1][g][2] * h[q][2];      \
            }                                                                  \
            float i0 = sigm(gv0[0]), f0 = sigm(gv0[1]);                        \
            float gg0 = tanh_(gv0[2]), o0 = sigm(gv0[3]);                      \
            float i1 = sigm(gv1[0]), f1 = sigm(gv1[1]);                        \
            float gg1 = tanh_(gv1[2]), o1 = sigm(gv1[3]);                      \
            c[q][0] = f0 * c[q][0] + i0 * gg0;                                 \
            c[q][1] = f1 * c[q][1] + i1 * gg1;                                 \
            float hr0 = o0 * tanh_(c[q][0]);                                   \
            float hr1 = o1 * tanh_(c[q][1]);                                   \
            float s0 = dpp_sum64(whr[0][0] * hr0 + whr[1][0] * hr1);           \
            float s1 = dpp_sum64(whr[0][1] * hr0 + whr[1][1] * hr1);           \
            float s2 = dpp_sum64(whr[0][2] * hr0 + whr[1][2] * hr1);           \
            h[q][0] = lane63(s0); h[q][1] = lane63(s1); h[q][2] = lane63(s2);  \
            if (DOW) {                                                         \
                if (lane < 3) {                                                \
                    float v = (lane == 0) ? h[q][0]                            \
                            : ((lane == 1) ? h[q][1] : h[q][2]);               \
                    size_t idx = (size_t)T[q] * 3 + lane;                      \
                    if (fp32out) outf[idx] = v; else outb[idx] = f2bf(v);      \
                }                                                              \
                T[q]++;                                                        \
            }                                                                  \
            LOADR(ring[q][S], trow[q])                                         \
            trow[q]++;                                                         \
        }                                                                      \
    }

    // Burn-in: steps 0..15 (slots 0,1,2,... ; step t uses slot t%3).
#pragma unroll 1
    for (int i = 0; i < 5; ++i) { STEP(0, 0) STEP(1, 0) STEP(2, 0) }
    STEP(0, 0)

    // Chunk 0 must start from the exact zero state.
    if (bid == 0) {
        h[0][0] = h[0][1] = h[0][2] = 0.f;
        c[0][0] = c[0][1] = 0.f;
    }

    // Write phase: steps 16..40 (slot sequence continues at 16%3 == 1).
    STEP(1, 1) STEP(2, 1)
#pragma unroll 1
    for (int i = 0; i < 7; ++i) { STEP(0, 1) STEP(1, 1) STEP(2, 1) }
    STEP(0, 1) STEP(1, 1)

#undef STEP
#undef LOADR

    if (bid == CHUNKS / 2 - 1) {          // chain 1 == chunk 1999 (global last)
        if (lane < 3) {
            float v = (lane == 0) ? h[1][0] : ((lane == 1) ? h[1][1] : h[1][2]);
            if (fp32out) outf[150000 + lane] = v; else outb[150000 + lane] = f2bf(v);
        }
        if (fp32out) {
            outf[150003 + ch0] = c[1][0];
            outf[150003 + ch0 + 1] = c[1][1];
        } else {
            outb[150003 + ch0] = f2bf(c[1][0]);
            outb[150003 + ch0 + 1] = f2bf(c[1][1]);
        }
    }
}

extern "C" void kernel_launch(void* const* d_in, const int* in_sizes, int n_in,
                              void* d_out, int out_size, void* d_ws, size_t ws_size,
                              hipStream_t stream)
{
    const int* ei = (const int*)d_in[1];
    const unsigned int* xprobe = (const unsigned int*)d_in[0];

    // ---- workspace layout (~64.7 MB) ----
    char* ws = (char*)d_ws;
    const size_t PRE_B  = (size_t)NN * 512 * 2;   // 51.2 MB
    const size_t NODE_B = (size_t)NN * 128 * 2;   // 12.8 MB
    unsigned short* pre  = (unsigned short*)ws;
    unsigned short* bufB = (unsigned short*)ws;                    // alias
    unsigned short* bufC = (unsigned short*)(ws + NODE_B);         // alias
    int* elist  = (int*)(ws + 2 * NODE_B);                         // alias, 2.4MB
    int* offs   = (int*)(ws + 2 * NODE_B + (size_t)NE * 4);        // NN+1 ints
    int* cursor = offs + (NN + 256);
    int* hist   = cursor + (NN + 256);
    int* tsum   = hist + (NN + 256);
    unsigned short* bufA = (unsigned short*)(ws + PRE_B);
    unsigned short* wbuf = (unsigned short*)(ws + PRE_B + NODE_B);

    // bf16 weight copies, element offsets into wbuf (matches cvt_w tables):
    unsigned short* Wp1 = wbuf + 0;      unsigned short* bp1 = wbuf + 16384;
    unsigned short* Wl1 = wbuf + 16512;  unsigned short* bl1 = wbuf + 32896;
    unsigned short* Wr1 = wbuf + 33024;
    unsigned short* Wp2 = wbuf + 49408;  unsigned short* bp2 = wbuf + 65792;
    unsigned short* Wl2 = wbuf + 65920;  unsigned short* bl2 = wbuf + 82304;
    unsigned short* Wr2 = wbuf + 82432;
    unsigned short* Wih = wbuf + 98816;  unsigned short* Whh = wbuf + 164352;
    unsigned short* bih = wbuf + 165888; unsigned short* bhh = wbuf + 166400;
    unsigned short* Whr = wbuf + 166912;

    dim3 b256(256), b1024(1024), b64(64);
    const size_t LDS1 = 32768, LDS2 = 65536;

    WSrc wsrc;
    {
        const int order[15] = {2,3,4,5,6,7,8,9,10,11,12,13,14,15,16};
        for (int i = 0; i < 15; ++i) wsrc.p[i] = d_in[order[i]];
    }

    hipMemsetAsync(hist, 0, (size_t)NN * 4, stream);

    // K1: hist || weight-convert
    k1_hist_cvtw<<<dim3(HISTB + 3840), b256, 0, stream>>>(ei, hist, wsrc, wbuf, xprobe);
    scanA_k<<<dim3(STILES), b1024, 0, stream>>>(hist, offs, tsum);
    scanC_k<<<dim3(STILES), b1024, 0, stream>>>(offs, cursor, tsum);

    // K4: fill || xp1-GEMM (independent: fill needs CSR, GEMM needs weights)
    k4_fill_gemm<<<dim3(HISTB + 782), b256, LDS1, stream>>>(
        ei, cursor, elist, d_in[0], Wp1, bp1, bufA);

    gather_mean_k<<<dim3(12500), b256, 0, stream>>>(offs, elist, bufA, bufC);
    gemm_k128<<<dim3(782, 1), b256, LDS2, stream>>>(bufC, d_in[0], Wl1, Wr1, bl1, nullptr,
                                                    bufB, NN, 1, 128, xprobe, 0, 1); // h1

    gemm_k128<<<dim3(782, 1), b256, LDS1, stream>>>(bufB, nullptr, Wp2, nullptr, bp2, nullptr,
                                                    bufA, NN, 1, 128, xprobe, 0, 0); // xp2
    gather_mean_k<<<dim3(12500), b256, 0, stream>>>(offs, elist, bufA, bufC);
    gemm_k128<<<dim3(782, 1), b256, LDS2, stream>>>(bufC, bufB, Wl2, Wr2, bl2, nullptr,
                                                    bufA, NN, 0, 128, xprobe, 0, 0); // h2

    // LSTM pre-activations: [N][512] row-major, coalesced writes
    gemm_k128<<<dim3(782, 4), b256, LDS1, stream>>>(bufA, nullptr, Wih, nullptr, bih, bhh,
                                                    pre, NN, 0, 512, xprobe, 0, 0);

    // LSTM: 2 chains/wave, 1000 blocks (R16)
    lstm_chunk_k<<<dim3(CHUNKS / 2), b64, 0, stream>>>(pre, Whh, Whr, d_out, xprobe);
}

// Round 3
// 368.228 us; speedup vs baseline: 1.0748x; 1.0748x over previous
//
#include <hip/hip_runtime.h>
#include <hip/hip_bf16.h>

// NodeSAGELSTM: 2x SAGEConv(project=True, mean aggr) + ReLU, then LSTM(proj=3).
//
// R18 == R17 resubmitted verbatim (previous round's bench died with
// "MI355X container failed twice" -- broker infra failure, no measurement).
//
// R17 theory (post-mortem of R16 @ 395.8us, lstm 81.3us, VALUBusy 39%, Occ 7.1%):
//  R16's 2-chains-per-wave halved TLP (2000->1000 waves) for a 1.54x per-wave
//  ILP gain (26%->40% issue/wave) -- net regression. The ring prefetch is the
//  part with no TLP cost. R17 = single chain per wave (2000 waves, ~2/SIMD)
//  + depth-3 rotating ring (use slot t%3, reload freed slot with row t+3;
//  ~3-step load->use lead vs R15's ~1-step shift register).
//  Chunk 0 uniform (clamped burn rows + state zero before write phase),
//  verified passing in R16. Everything else identical to R15/R16.

#define NN 50000
#define NE 600000
#define CHUNKS 2000
#define CLEN 25
#define BURN 16

typedef __attribute__((ext_vector_type(8))) short bf16x8;
typedef __attribute__((ext_vector_type(4))) float f32x4;

__device__ __forceinline__ float bf2f(unsigned short u) {
    union { unsigned int i; float f; } v; v.i = ((unsigned int)u) << 16; return v.f;
}
__device__ __forceinline__ unsigned short f2bf(float f) {
    union { float f; unsigned int i; } v; v.f = f;
    unsigned int x = v.i;
    return (unsigned short)((x + 0x7FFFu + ((x >> 16) & 1u)) >> 16);
}
__device__ __forceinline__ float sigm(float x) { return 1.f / (1.f + __expf(-x)); }
__device__ __forceinline__ float tanh_(float x) {
    float t = __expf(2.f * x);          // saturates cleanly at +-1
    return 1.f - 2.f / (t + 1.f);
}

// Self-detection (uniform, branch-free, L1-cached probes).
__device__ __forceinline__ bool detect_fp32(const unsigned int* __restrict__ xw) {
    int cnt = 0;
#pragma unroll
    for (int i = 0; i < 32; ++i) {
        float av = fabsf(bf2f((unsigned short)(xw[i] & 0xFFFFu)));
        cnt += (av > 1e-6f && av < 1e4f) ? 1 : 0;
    }
    return cnt < 16;
}
__device__ __forceinline__ bool detect_is64(const int* __restrict__ ei) {
    bool z = true;
#pragma unroll
    for (int i = 1; i < 16; i += 2) z = z && (ei[i] == 0);
    return z;
}

// 64-lane sum via DPP (row_shr 1/2/4/8 + row_bcast 15/31); result in lane 63.
__device__ __forceinline__ float dpp_sum64(float x) {
    int v;
    v = __builtin_amdgcn_update_dpp(0, __float_as_int(x), 0x111, 0xf, 0xf, true);
    x += __int_as_float(v);
    v = __builtin_amdgcn_update_dpp(0, __float_as_int(x), 0x112, 0xf, 0xf, true);
    x += __int_as_float(v);
    v = __builtin_amdgcn_update_dpp(0, __float_as_int(x), 0x114, 0xf, 0xf, true);
    x += __int_as_float(v);
    v = __builtin_amdgcn_update_dpp(0, __float_as_int(x), 0x118, 0xf, 0xf, true);
    x += __int_as_float(v);
    v = __builtin_amdgcn_update_dpp(0, __float_as_int(x), 0x142, 0xa, 0xf, true);
    x += __int_as_float(v);
    v = __builtin_amdgcn_update_dpp(0, __float_as_int(x), 0x143, 0xc, 0xf, true);
    x += __int_as_float(v);
    return x;
}
__device__ __forceinline__ float lane63(float x) {
    return __int_as_float(__builtin_amdgcn_readlane(__float_as_int(x), 63));
}

__device__ __forceinline__ int clampn(int v) {
    v = v < 0 ? 0 : v; return v >= NN ? NN - 1 : v;
}
__device__ __forceinline__ int edst(const int* ei, int e, bool is64) {
    return clampn(is64 ? ei[2 * NE + 2 * e] : ei[NE + e]);
}
__device__ __forceinline__ int esrc(const int* ei, int e, bool is64) {
    return clampn(is64 ? ei[2 * e] : ei[e]);
}

// ---- weight conversion (device body; called from fused K1) ----
struct WSrc { const void* p[15]; };
__device__ __forceinline__ void cvt_w_body(
    const WSrc& sp, unsigned short* __restrict__ wbuf, bool f32,
    int seg, int i)
{
    static const int segoff[15] = {0, 16384, 16512, 32896, 33024, 49408, 65792,
                                   65920, 82304, 82432, 98816, 164352, 165888,
                                   166400, 166912};
    static const int segn[15]   = {16384, 128, 16384, 128, 16384, 16384, 128,
                                   16384, 128, 16384, 65536, 1536, 512, 512, 384};
    static const int segmat[15] = {1, 0, 1, 0, 1, 1, 0, 1, 0, 1, 1, 0, 0, 0, 0};
    if (i >= segn[seg]) return;
    float val;
    if (f32) val = ((const float*)sp.p[seg])[i];
    else     val = bf2f(((const unsigned short*)sp.p[seg])[i]);
    int dst = i;
    if (segmat[seg]) {
        int row = i >> 7, kcol = i & 127;
        int tile = row >> 7, r = row & 127;
        int c = r >> 4, m = r & 15;
        int ks = kcol >> 5, kh = (kcol >> 3) & 3, j = kcol & 7;
        dst = (tile << 14) + (((c << 8) + (ks << 6) + (kh << 4) + m) << 3) + j;
    }
    wbuf[segoff[seg] + dst] = f2bf(val);
}

#define HISTB 2344   // ceil(600000/256)

// K1: hist (blocks [0,HISTB)) || weight convert (blocks [HISTB, HISTB+3840))
__global__ __launch_bounds__(256) void k1_hist_cvtw(
    const int* __restrict__ ei, int* __restrict__ hist,
    WSrc sp, unsigned short* __restrict__ wbuf,
    const unsigned int* __restrict__ xprobe)
{
    int bid = blockIdx.x;
    if (bid < HISTB) {
        bool is64 = detect_is64(ei);
        int e = bid * 256 + threadIdx.x;
        if (e < NE) atomicAdd(hist + edst(ei, e, is64), 1);
    } else {
        int b2 = bid - HISTB;
        int seg = b2 >> 8;
        int i = (b2 & 255) * 256 + threadIdx.x;
        bool f32 = detect_fp32(xprobe);
        cvt_w_body(sp, wbuf, f32, seg, i);
    }
}

#define STILES 49   // ceil(50000/1024)

__global__ __launch_bounds__(1024) void scanA_k(
    const int* __restrict__ hist, int* __restrict__ offs, int* __restrict__ tsum)
{
    __shared__ int sh[1024];
    int t = threadIdx.x, idx = blockIdx.x * 1024 + t;
    int v = (idx < NN) ? hist[idx] : 0;
    sh[t] = v;
    __syncthreads();
    int acc = v;
    for (int off = 1; off < 1024; off <<= 1) {
        int y = (t >= off) ? sh[t - off] : 0;
        __syncthreads();
        acc += y; sh[t] = acc;
        __syncthreads();
    }
    if (idx < NN) offs[idx] = acc - v;            // exclusive within tile
    if (t == 1023) tsum[blockIdx.x] = acc;        // tile total
}

__global__ __launch_bounds__(1024) void scanC_k(
    int* __restrict__ offs, int* __restrict__ cursor, const int* __restrict__ tsum)
{
    __shared__ int sbase;
    int t = threadIdx.x;
    if (t < 64) {
        int v = (t < STILES && t < (int)blockIdx.x) ? tsum[t] : 0;
#pragma unroll
        for (int off = 32; off > 0; off >>= 1) v += __shfl_xor(v, off, 64);
        if (t == 0) sbase = v;
    }
    __syncthreads();
    int idx = blockIdx.x * 1024 + t;
    if (idx < NN) {
        int o = offs[idx] + sbase;
        offs[idx] = o; cursor[idx] = o;
    }
    if (blockIdx.x == STILES - 1 && t == 0) offs[NN] = NE;
}

// A-fragment load: bf16x8 from bf16 buffer, or inline-convert from fp32 input.
__device__ __forceinline__ bf16x8 load_a8(const void* A, size_t off, bool f32) {
    if (f32) {
        const float* pf = (const float*)A + off;
        f32x4 u0 = *(const f32x4*)pf;
        f32x4 u1 = *(const f32x4*)(pf + 4);
        bf16x8 r;
        r[0] = (short)f2bf(u0[0]); r[1] = (short)f2bf(u0[1]);
        r[2] = (short)f2bf(u0[2]); r[3] = (short)f2bf(u0[3]);
        r[4] = (short)f2bf(u1[0]); r[5] = (short)f2bf(u1[1]);
        r[6] = (short)f2bf(u1[2]); r[7] = (short)f2bf(u1[3]);
        return r;
    }
    return *(const bf16x8*)((const unsigned short*)A + off);
}

// GEMM body (R11 structure): W/W2 in fragment order, staged to LDS (flat int4
// copy); B-fragments via conflict-free contiguous ds_read_b128; A-loads
// hoisted above the staging barrier.
__device__ __forceinline__ void gemm_body(
    char* smem, int bidx, int cb,
    const void* __restrict__ A, const void* __restrict__ A2,
    const unsigned short* __restrict__ W, const unsigned short* __restrict__ W2,
    const unsigned short* __restrict__ b1, const unsigned short* __restrict__ b2,
    unsigned short* __restrict__ out,
    int n_rows, int relu_flag, int out_stride, bool af32, bool a2f32)
{
    const int tid  = threadIdx.x;
    const int lane = tid & 63;
    const int wv   = tid >> 6;
    const int row0 = bidx * 64 + wv * 16;
    const int m    = lane & 15;
    const int kh   = lane >> 4;

    int arow = row0 + m; if (arow >= n_rows) arow = n_rows - 1;
    const size_t aoff = (size_t)arow * 128 + kh * 8;

    bf16x8 a[4], a2v[4];
#pragma unroll
    for (int ks = 0; ks < 4; ++ks) a[ks] = load_a8(A, aoff + ks * 32, af32);
    if (A2) {
#pragma unroll
        for (int ks = 0; ks < 4; ++ks) a2v[ks] = load_a8(A2, aoff + ks * 32, a2f32);
    }

    {
        const unsigned short* wt = W + (size_t)cb * 16384;
        int4 tmp[8];
#pragma unroll
        for (int q = 0; q < 8; ++q)
            tmp[q] = *(const int4*)(wt + (size_t)(tid + q * 256) * 8);
#pragma unroll
        for (int q = 0; q < 8; ++q)
            *(int4*)(smem + (size_t)(tid + q * 256) * 16) = tmp[q];
        if (W2) {
            const unsigned short* w2t = W2 + (size_t)cb * 16384;
            int4 tm2[8];
#pragma unroll
            for (int q = 0; q < 8; ++q)
                tm2[q] = *(const int4*)(w2t + (size_t)(tid + q * 256) * 8);
#pragma unroll
            for (int q = 0; q < 8; ++q)
                *(int4*)(smem + 32768 + (size_t)(tid + q * 256) * 16) = tm2[q];
        }
    }
    __syncthreads();

    f32x4 acc[8];
#pragma unroll
    for (int c = 0; c < 8; ++c) acc[c] = (f32x4){0.f, 0.f, 0.f, 0.f};

#pragma unroll
    for (int ks = 0; ks < 4; ++ks) {
#pragma unroll
        for (int c = 0; c < 8; ++c) {
            bf16x8 b = *(const bf16x8*)(smem + (size_t)(c * 256 + ks * 64 + lane) * 16);
            acc[c] = __builtin_amdgcn_mfma_f32_16x16x32_bf16(a[ks], b, acc[c], 0, 0, 0);
        }
        if (W2) {
#pragma unroll
            for (int c = 0; c < 8; ++c) {
                bf16x8 b2 = *(const bf16x8*)(smem + 32768 +
                                             (size_t)(c * 256 + ks * 64 + lane) * 16);
                acc[c] = __builtin_amdgcn_mfma_f32_16x16x32_bf16(a2v[ks], b2, acc[c], 0, 0, 0);
            }
        }
    }

#pragma unroll
    for (int c = 0; c < 8; ++c) {
        int col = cb * 128 + c * 16 + m;    // C/D: col = lane&15
        float bias = 0.f;
        if (b1) bias += bf2f(b1[col]);
        if (b2) bias += bf2f(b2[col]);
#pragma unroll
        for (int r = 0; r < 4; ++r) {
            int row = row0 + kh * 4 + r;    // C/D: row = (lane>>4)*4 + reg
            if (row >= n_rows) continue;
            float v = acc[c][r] + bias;
            if (relu_flag && v < 0.f) v = 0.f;
            out[(size_t)row * out_stride + col] = f2bf(v);
        }
    }
}

__global__ __launch_bounds__(256) void gemm_k128(
    const void* __restrict__ A,
    const void* __restrict__ A2,
    const unsigned short* __restrict__ W,
    const unsigned short* __restrict__ W2,
    const unsigned short* __restrict__ b1,
    const unsigned short* __restrict__ b2,
    unsigned short* __restrict__ out,
    int n_rows, int relu_flag, int out_stride,
    const unsigned int* __restrict__ xprobe, int a_sel, int a2_sel)
{
    extern __shared__ __align__(16) char smem[];
    bool f32 = (a_sel | a2_sel) ? detect_fp32(xprobe) : false;
    gemm_body(smem, blockIdx.x, blockIdx.y, A, A2, W, W2, b1, b2, out,
              n_rows, relu_flag, out_stride, a_sel && f32, a2_sel && f32);
}

// K4: fill (blocks [0,HISTB)) || xp1-GEMM (blocks [HISTB, HISTB+782))
__global__ __launch_bounds__(256) void k4_fill_gemm(
    const int* __restrict__ ei, int* __restrict__ cursor, int* __restrict__ elist,
    const void* __restrict__ x,
    const unsigned short* __restrict__ Wp1, const unsigned short* __restrict__ bp1,
    unsigned short* __restrict__ bufA)
{
    extern __shared__ __align__(16) char smem[];
    int bid = blockIdx.x;
    if (bid < HISTB) {
        bool is64 = detect_is64(ei);
        int e = bid * 256 + threadIdx.x;
        if (e >= NE) return;
        int p = atomicAdd(cursor + edst(ei, e, is64), 1);
        elist[p] = esrc(ei, e, is64);
    } else {
        bool f32 = detect_fp32((const unsigned int*)x);
        gemm_body(smem, bid - HISTB, 0, x, nullptr, Wp1, nullptr, bp1, nullptr,
                  bufA, NN, 1, 128, f32, false);
    }
}

// One wave per node: mean over incoming src rows of xp (bf16), write bf16.
__global__ __launch_bounds__(256) void gather_mean_k(
    const int* __restrict__ offs, const int* __restrict__ elist,
    const unsigned short* __restrict__ xp, unsigned short* __restrict__ out)
{
    const int node = blockIdx.x * 4 + (threadIdx.x >> 6);
    const int lane = threadIdx.x & 63;
    if (node >= NN) return;
    const int beg = offs[node], end = offs[node + 1];
    float a0 = 0.f, a1 = 0.f;
    int e = beg;
    for (; e + 4 <= end; e += 4) {
        int s0 = elist[e], s1 = elist[e + 1], s2 = elist[e + 2], s3 = elist[e + 3];
        unsigned int w0 = *(const unsigned int*)(xp + (size_t)s0 * 128 + lane * 2);
        unsigned int w1 = *(const unsigned int*)(xp + (size_t)s1 * 128 + lane * 2);
        unsigned int w2 = *(const unsigned int*)(xp + (size_t)s2 * 128 + lane * 2);
        unsigned int w3 = *(const unsigned int*)(xp + (size_t)s3 * 128 + lane * 2);
        a0 += bf2f((unsigned short)(w0 & 0xFFFFu)) + bf2f((unsigned short)(w1 & 0xFFFFu))
            + bf2f((unsigned short)(w2 & 0xFFFFu)) + bf2f((unsigned short)(w3 & 0xFFFFu));
        a1 += bf2f((unsigned short)(w0 >> 16)) + bf2f((unsigned short)(w1 >> 16))
            + bf2f((unsigned short)(w2 >> 16)) + bf2f((unsigned short)(w3 >> 16));
    }
    for (; e < end; ++e) {
        int s = elist[e];
        unsigned int w = *(const unsigned int*)(xp + (size_t)s * 128 + lane * 2);
        a0 += bf2f((unsigned short)(w & 0xFFFFu));
        a1 += bf2f((unsigned short)(w >> 16));
    }
    int cnt = end - beg;
    float inv = 1.f / (float)(cnt > 1 ? cnt : 1);
    unsigned int o = (unsigned int)f2bf(a0 * inv) | ((unsigned int)f2bf(a1 * inv) << 16);
    *(unsigned int*)(out + (size_t)node * 128 + lane * 2) = o;
}

// LSTM R17: one chunk per wave (2000 waves, ~2/SIMD TLP restored) + depth-3
// rotating ring prefetch: step t uses ring slot t%3, then reloads that slot
// with row t+3 (3-step load->use lead; R15's shift register consumed its
// newest load within ~1 step). Lane l owns channels (2l,2l+1).
// Chunk 0 burns on row-clamped reads and state is zeroed before the write
// phase (recurrence bitwise identical to R15; verified in R16).
// Prefetch overrun for the last chunk reads rows NN..NN+2 (bufA region,
// valid mapped ws memory, values never consumed).
__global__ __launch_bounds__(64) void lstm_chunk_k(
    const unsigned short* __restrict__ pre,
    const unsigned short* __restrict__ Whh,   // [512,3] bf16
    const unsigned short* __restrict__ Whr,   // [3,128] bf16
    void* __restrict__ outv,                  // d_out: hs[150000], hN[3], cN[128]
    const unsigned int* __restrict__ xprobe)
{
    const int m = blockIdx.x;
    const int lane = threadIdx.x;
    const bool fp32out = detect_fp32(xprobe);
    float* outf = (float*)outv;
    unsigned short* outb = (unsigned short*)outv;
    const int ch0 = 2 * lane;

    float whh[2][4][3];
#pragma unroll
    for (int j = 0; j < 2; ++j)
#pragma unroll
        for (int g = 0; g < 4; ++g)
#pragma unroll
            for (int k = 0; k < 3; ++k)
                whh[j][g][k] = bf2f(Whh[(g * 128 + ch0 + j) * 3 + k]);
    float whr[2][3];
#pragma unroll
    for (int j = 0; j < 2; ++j)
#pragma unroll
        for (int k = 0; k < 3; ++k)
            whr[j][k] = bf2f(Whr[k * 128 + ch0 + j]);

    const int t0 = m * CLEN;
    const int ts = t0 - BURN;              // m==0: -16, rows clamp to 0

    float ring[3][2][4];
    float h0 = 0.f, h1 = 0.f, h2 = 0.f, c0 = 0.f, c1 = 0.f;
    int T = t0;

// Load row r (clamped at 0 for chunk-0's fake burn) into a [2][4] slot.
#define LOADR(dst, r)                                                          \
    {                                                                          \
        const unsigned short* _pp = pre + ((size_t)((r) > 0 ? (r) : 0) << 9);  \
        _Pragma("unroll")                                                      \
        for (int g = 0; g < 4; ++g) {                                          \
            unsigned int w = *(const unsigned int*)(_pp + g * 128 + ch0);      \
            dst[0][g] = bf2f((unsigned short)(w & 0xFFFFu));                   \
            dst[1][g] = bf2f((unsigned short)(w >> 16));                       \
        }                                                                      \
    }

    LOADR(ring[0], ts)
    LOADR(ring[1], ts + 1)
    LOADR(ring[2], ts + 2)
    int trow = ts + 3;

// One LSTM step: consume ring slot S, then reload S with row trow
// (consumed 3 steps later).
#define STEP(S, DOW)                                                           \
    {                                                                          \
        float gv0[4], gv1[4];                                                  \
        _Pragma("unroll")                                                      \
        for (int g = 0; g < 4; ++g) {                                          \
            gv0[g] = ring[S][0][g] + whh[0][g][0] * h0 + whh[0][g][1] * h1     \
                   + whh[0][g][2] * h2;                                        \
            gv1[g] = ring[S][1][g] + whh[1][g][0] * h0 + whh[1][g][1] * h1     \
                   + whh[1][g][2] * h2;                                        \
        }                                                                      \
        float i0 = sigm(gv0[0]), f0 = sigm(gv0[1]);                            \
        float gg0 = tanh_(gv0[2]), o0 = sigm(gv0[3]);                          \
        float i1 = sigm(gv1[0]), f1 = sigm(gv1[1]);                            \
        float gg1 = tanh_(gv1[2]), o1 = sigm(gv1[3]);                          \
        c0 = f0 * c0 + i0 * gg0;                                               \
        c1 = f1 * c1 + i1 * gg1;                                               \
        float hr0 = o0 * tanh_(c0);                                            \
        float hr1 = o1 * tanh_(c1);                                            \
        float s0 = dpp_sum64(whr[0][0] * hr0 + whr[1][0] * hr1);               \
        float s1 = dpp_sum64(whr[0][1] * hr0 + whr[1][1] * hr1);               \
        float s2 = dpp_sum64(whr[0][2] * hr0 + whr[1][2] * hr1);               \
        h0 = lane63(s0); h1 = lane63(s1); h2 = lane63(s2);                     \
        if (DOW) {                                                             \
            if (lane < 3) {                                                    \
                float v = (lane == 0) ? h0 : ((lane == 1) ? h1 : h2);          \
                size_t idx = (size_t)T * 3 + lane;                             \
                if (fp32out) outf[idx] = v; else outb[idx] = f2bf(v);          \
            }                                                                  \
            T++;                                                               \
        }                                                                      \
        LOADR(ring[S], trow)                                                   \
        trow++;                                                                \
    }

    // Burn-in: steps 0..15 (step t uses slot t%3); all chunks burn; chunk 0
    // burns on clamped row-0 reads, then resets to the exact zero state.
#pragma unroll 1
    for (int i = 0; i < 5; ++i) { STEP(0, 0) STEP(1, 0) STEP(2, 0) }
    STEP(0, 0)

    if (m == 0) { h0 = h1 = h2 = 0.f; c0 = c1 = 0.f; }

    // Write phase: steps 16..40 (slot sequence continues at 16%3 == 1).
    STEP(1, 1) STEP(2, 1)
#pragma unroll 1
    for (int i = 0; i < 7; ++i) { STEP(0, 1) STEP(1, 1) STEP(2, 1) }
    STEP(0, 1) STEP(1, 1)

#undef STEP
#undef LOADR

    if (m == CHUNKS - 1) {
        if (lane < 3) {
            float v = (lane == 0) ? h0 : ((lane == 1) ? h1 : h2);
            if (fp32out) outf[150000 + lane] = v; else outb[150000 + lane] = f2bf(v);
        }
        if (fp32out) {
            outf[150003 + ch0] = c0;
            outf[150003 + ch0 + 1] = c1;
        } else {
            outb[150003 + ch0] = f2bf(c0);
            outb[150003 + ch0 + 1] = f2bf(c1);
        }
    }
}

extern "C" void kernel_launch(void* const* d_in, const int* in_sizes, int n_in,
                              void* d_out, int out_size, void* d_ws, size_t ws_size,
                              hipStream_t stream)
{
    const int* ei = (const int*)d_in[1];
    const unsigned int* xprobe = (const unsigned int*)d_in[0];

    // ---- workspace layout (~64.7 MB) ----
    char* ws = (char*)d_ws;
    const size_t PRE_B  = (size_t)NN * 512 * 2;   // 51.2 MB
    const size_t NODE_B = (size_t)NN * 128 * 2;   // 12.8 MB
    unsigned short* pre  = (unsigned short*)ws;
    unsigned short* bufB = (unsigned short*)ws;                    // alias
    unsigned short* bufC = (unsigned short*)(ws + NODE_B);         // alias
    int* elist  = (int*)(ws + 2 * NODE_B);                         // alias, 2.4MB
    int* offs   = (int*)(ws + 2 * NODE_B + (size_t)NE * 4);        // NN+1 ints
    int* cursor = offs + (NN + 256);
    int* hist   = cursor + (NN + 256);
    int* tsum   = hist + (NN + 256);
    unsigned short* bufA = (unsigned short*)(ws + PRE_B);
    unsigned short* wbuf = (unsigned short*)(ws + PRE_B + NODE_B);

    // bf16 weight copies, element offsets into wbuf (matches cvt_w tables):
    unsigned short* Wp1 = wbuf + 0;      unsigned short* bp1 = wbuf + 16384;
    unsigned short* Wl1 = wbuf + 16512;  unsigned short* bl1 = wbuf + 32896;
    unsigned short* Wr1 = wbuf + 33024;
    unsigned short* Wp2 = wbuf + 49408;  unsigned short* bp2 = wbuf + 65792;
    unsigned short* Wl2 = wbuf + 65920;  unsigned short* bl2 = wbuf + 82304;
    unsigned short* Wr2 = wbuf + 82432;
    unsigned short* Wih = wbuf + 98816;  unsigned short* Whh = wbuf + 164352;
    unsigned short* bih = wbuf + 165888; unsigned short* bhh = wbuf + 166400;
    unsigned short* Whr = wbuf + 166912;

    dim3 b256(256), b1024(1024), b64(64);
    const size_t LDS1 = 32768, LDS2 = 65536;

    WSrc wsrc;
    {
        const int order[15] = {2,3,4,5,6,7,8,9,10,11,12,13,14,15,16};
        for (int i = 0; i < 15; ++i) wsrc.p[i] = d_in[order[i]];
    }

    hipMemsetAsync(hist, 0, (size_t)NN * 4, stream);

    // K1: hist || weight-convert
    k1_hist_cvtw<<<dim3(HISTB + 3840), b256, 0, stream>>>(ei, hist, wsrc, wbuf, xprobe);
    scanA_k<<<dim3(STILES), b1024, 0, stream>>>(hist, offs, tsum);
    scanC_k<<<dim3(STILES), b1024, 0, stream>>>(offs, cursor, tsum);

    // K4: fill || xp1-GEMM (independent: fill needs CSR, GEMM needs weights)
    k4_fill_gemm<<<dim3(HISTB + 782), b256, LDS1, stream>>>(
        ei, cursor, elist, d_in[0], Wp1, bp1, bufA);

    gather_mean_k<<<dim3(12500), b256, 0, stream>>>(offs, elist, bufA, bufC);
    gemm_k128<<<dim3(782, 1), b256, LDS2, stream>>>(bufC, d_in[0], Wl1, Wr1, bl1, nullptr,
                                                    bufB, NN, 1, 128, xprobe, 0, 1); // h1

    gemm_k128<<<dim3(782, 1), b256, LDS1, stream>>>(bufB, nullptr, Wp2, nullptr, bp2, nullptr,
                                                    bufA, NN, 1, 128, xprobe, 0, 0); // xp2
    gather_mean_k<<<dim3(12500), b256, 0, stream>>>(offs, elist, bufA, bufC);
    gemm_k128<<<dim3(782, 1), b256, LDS2, stream>>>(bufC, bufB, Wl2, Wr2, bl2, nullptr,
                                                    bufA, NN, 0, 128, xprobe, 0, 0); // h2

    // LSTM pre-activations: [N][512] row-major, coalesced writes
    gemm_k128<<<dim3(782, 4), b256, LDS1, stream>>>(bufA, nullptr, Wih, nullptr, bih, bhh,
                                                    pre, NN, 0, 512, xprobe, 0, 0);

    // LSTM: one chunk per wave + depth-3 ring (R17/R18)
    lstm_chunk_k<<<dim3(CHUNKS), b64, 0, stream>>>(pre, Whh, Whr, d_out, xprobe);
}

// Round 4
// 359.110 us; speedup vs baseline: 1.1021x; 1.0254x over previous
//
#include <hip/hip_runtime.h>
#include <hip/hip_bf16.h>

// NodeSAGELSTM: 2x SAGEConv(project=True, mean aggr) + ReLU, then LSTM(proj=3).
//
// R19 (post-mortem R17/R18 @ 368.2us, lstm 62.3us, VALUBusy 50%, Occ 12.2%):
//  Evidence triangulation: ring prefetch (R17) = no change -> not memory-bound;
//  2x in-wave ILP (R16) = per-SIMD throughput DROPPED -> compiler can't fill
//  dependency stalls within a wave (DPP/readlane regions serialize). The ~50%
//  idle is dependency latency fillable only by OTHER WAVES. Occupancy counter
//  says only ~3.9 waves/CU resident despite 7.8 single-wave blocks/CU launched
//  -> suspect workgroup-slot/dispatch limit on 64-thread blocks.
//  R19: repackage the SAME 2000 chunks as 500 blocks x 256 threads (4
//  independent waves per block, one chunk per wave; no barriers, no LDS).
//  Total work, per-wave code and numerics bitwise unchanged.
//  Everything outside the LSTM launch shape is identical to R17/R18.

#define NN 50000
#define NE 600000
#define CHUNKS 2000
#define CLEN 25
#define BURN 16

typedef __attribute__((ext_vector_type(8))) short bf16x8;
typedef __attribute__((ext_vector_type(4))) float f32x4;

__device__ __forceinline__ float bf2f(unsigned short u) {
    union { unsigned int i; float f; } v; v.i = ((unsigned int)u) << 16; return v.f;
}
__device__ __forceinline__ unsigned short f2bf(float f) {
    union { float f; unsigned int i; } v; v.f = f;
    unsigned int x = v.i;
    return (unsigned short)((x + 0x7FFFu + ((x >> 16) & 1u)) >> 16);
}
__device__ __forceinline__ float sigm(float x) { return 1.f / (1.f + __expf(-x)); }
__device__ __forceinline__ float tanh_(float x) {
    float t = __expf(2.f * x);          // saturates cleanly at +-1
    return 1.f - 2.f / (t + 1.f);
}

// Self-detection (uniform, branch-free, L1-cached probes).
__device__ __forceinline__ bool detect_fp32(const unsigned int* __restrict__ xw) {
    int cnt = 0;
#pragma unroll
    for (int i = 0; i < 32; ++i) {
        float av = fabsf(bf2f((unsigned short)(xw[i] & 0xFFFFu)));
        cnt += (av > 1e-6f && av < 1e4f) ? 1 : 0;
    }
    return cnt < 16;
}
__device__ __forceinline__ bool detect_is64(const int* __restrict__ ei) {
    bool z = true;
#pragma unroll
    for (int i = 1; i < 16; i += 2) z = z && (ei[i] == 0);
    return z;
}

// 64-lane sum via DPP (row_shr 1/2/4/8 + row_bcast 15/31); result in lane 63.
__device__ __forceinline__ float dpp_sum64(float x) {
    int v;
    v = __builtin_amdgcn_update_dpp(0, __float_as_int(x), 0x111, 0xf, 0xf, true);
    x += __int_as_float(v);
    v = __builtin_amdgcn_update_dpp(0, __float_as_int(x), 0x112, 0xf, 0xf, true);
    x += __int_as_float(v);
    v = __builtin_amdgcn_update_dpp(0, __float_as_int(x), 0x114, 0xf, 0xf, true);
    x += __int_as_float(v);
    v = __builtin_amdgcn_update_dpp(0, __float_as_int(x), 0x118, 0xf, 0xf, true);
    x += __int_as_float(v);
    v = __builtin_amdgcn_update_dpp(0, __float_as_int(x), 0x142, 0xa, 0xf, true);
    x += __int_as_float(v);
    v = __builtin_amdgcn_update_dpp(0, __float_as_int(x), 0x143, 0xc, 0xf, true);
    x += __int_as_float(v);
    return x;
}
__device__ __forceinline__ float lane63(float x) {
    return __int_as_float(__builtin_amdgcn_readlane(__float_as_int(x), 63));
}

__device__ __forceinline__ int clampn(int v) {
    v = v < 0 ? 0 : v; return v >= NN ? NN - 1 : v;
}
__device__ __forceinline__ int edst(const int* ei, int e, bool is64) {
    return clampn(is64 ? ei[2 * NE + 2 * e] : ei[NE + e]);
}
__device__ __forceinline__ int esrc(const int* ei, int e, bool is64) {
    return clampn(is64 ? ei[2 * e] : ei[e]);
}

// ---- weight conversion (device body; called from fused K1) ----
struct WSrc { const void* p[15]; };
__device__ __forceinline__ void cvt_w_body(
    const WSrc& sp, unsigned short* __restrict__ wbuf, bool f32,
    int seg, int i)
{
    static const int segoff[15] = {0, 16384, 16512, 32896, 33024, 49408, 65792,
                                   65920, 82304, 82432, 98816, 164352, 165888,
                                   166400, 166912};
    static const int segn[15]   = {16384, 128, 16384, 128, 16384, 16384, 128,
                                   16384, 128, 16384, 65536, 1536, 512, 512, 384};
    static const int segmat[15] = {1, 0, 1, 0, 1, 1, 0, 1, 0, 1, 1, 0, 0, 0, 0};
    if (i >= segn[seg]) return;
    float val;
    if (f32) val = ((const float*)sp.p[seg])[i];
    else     val = bf2f(((const unsigned short*)sp.p[seg])[i]);
    int dst = i;
    if (segmat[seg]) {
        int row = i >> 7, kcol = i & 127;
        int tile = row >> 7, r = row & 127;
        int c = r >> 4, m = r & 15;
        int ks = kcol >> 5, kh = (kcol >> 3) & 3, j = kcol & 7;
        dst = (tile << 14) + (((c << 8) + (ks << 6) + (kh << 4) + m) << 3) + j;
    }
    wbuf[segoff[seg] + dst] = f2bf(val);
}

#define HISTB 2344   // ceil(600000/256)

// K1: hist (blocks [0,HISTB)) || weight convert (blocks [HISTB, HISTB+3840))
__global__ __launch_bounds__(256) void k1_hist_cvtw(
    const int* __restrict__ ei, int* __restrict__ hist,
    WSrc sp, unsigned short* __restrict__ wbuf,
    const unsigned int* __restrict__ xprobe)
{
    int bid = blockIdx.x;
    if (bid < HISTB) {
        bool is64 = detect_is64(ei);
        int e = bid * 256 + threadIdx.x;
        if (e < NE) atomicAdd(hist + edst(ei, e, is64), 1);
    } else {
        int b2 = bid - HISTB;
        int seg = b2 >> 8;
        int i = (b2 & 255) * 256 + threadIdx.x;
        bool f32 = detect_fp32(xprobe);
        cvt_w_body(sp, wbuf, f32, seg, i);
    }
}

#define STILES 49   // ceil(50000/1024)

__global__ __launch_bounds__(1024) void scanA_k(
    const int* __restrict__ hist, int* __restrict__ offs, int* __restrict__ tsum)
{
    __shared__ int sh[1024];
    int t = threadIdx.x, idx = blockIdx.x * 1024 + t;
    int v = (idx < NN) ? hist[idx] : 0;
    sh[t] = v;
    __syncthreads();
    int acc = v;
    for (int off = 1; off < 1024; off <<= 1) {
        int y = (t >= off) ? sh[t - off] : 0;
        __syncthreads();
        acc += y; sh[t] = acc;
        __syncthreads();
    }
    if (idx < NN) offs[idx] = acc - v;            // exclusive within tile
    if (t == 1023) tsum[blockIdx.x] = acc;        // tile total
}

__global__ __launch_bounds__(1024) void scanC_k(
    int* __restrict__ offs, int* __restrict__ cursor, const int* __restrict__ tsum)
{
    __shared__ int sbase;
    int t = threadIdx.x;
    if (t < 64) {
        int v = (t < STILES && t < (int)blockIdx.x) ? tsum[t] : 0;
#pragma unroll
        for (int off = 32; off > 0; off >>= 1) v += __shfl_xor(v, off, 64);
        if (t == 0) sbase = v;
    }
    __syncthreads();
    int idx = blockIdx.x * 1024 + t;
    if (idx < NN) {
        int o = offs[idx] + sbase;
        offs[idx] = o; cursor[idx] = o;
    }
    if (blockIdx.x == STILES - 1 && t == 0) offs[NN] = NE;
}

// A-fragment load: bf16x8 from bf16 buffer, or inline-convert from fp32 input.
__device__ __forceinline__ bf16x8 load_a8(const void* A, size_t off, bool f32) {
    if (f32) {
        const float* pf = (const float*)A + off;
        f32x4 u0 = *(const f32x4*)pf;
        f32x4 u1 = *(const f32x4*)(pf + 4);
        bf16x8 r;
        r[0] = (short)f2bf(u0[0]); r[1] = (short)f2bf(u0[1]);
        r[2] = (short)f2bf(u0[2]); r[3] = (short)f2bf(u0[3]);
        r[4] = (short)f2bf(u1[0]); r[5] = (short)f2bf(u1[1]);
        r[6] = (short)f2bf(u1[2]); r[7] = (short)f2bf(u1[3]);
        return r;
    }
    return *(const bf16x8*)((const unsigned short*)A + off);
}

// GEMM body (R11 structure): W/W2 in fragment order, staged to LDS (flat int4
// copy); B-fragments via conflict-free contiguous ds_read_b128; A-loads
// hoisted above the staging barrier.
__device__ __forceinline__ void gemm_body(
    char* smem, int bidx, int cb,
    const void* __restrict__ A, const void* __restrict__ A2,
    const unsigned short* __restrict__ W, const unsigned short* __restrict__ W2,
    const unsigned short* __restrict__ b1, const unsigned short* __restrict__ b2,
    unsigned short* __restrict__ out,
    int n_rows, int relu_flag, int out_stride, bool af32, bool a2f32)
{
    const int tid  = threadIdx.x;
    const int lane = tid & 63;
    const int wv   = tid >> 6;
    const int row0 = bidx * 64 + wv * 16;
    const int m    = lane & 15;
    const int kh   = lane >> 4;

    int arow = row0 + m; if (arow >= n_rows) arow = n_rows - 1;
    const size_t aoff = (size_t)arow * 128 + kh * 8;

    bf16x8 a[4], a2v[4];
#pragma unroll
    for (int ks = 0; ks < 4; ++ks) a[ks] = load_a8(A, aoff + ks * 32, af32);
    if (A2) {
#pragma unroll
        for (int ks = 0; ks < 4; ++ks) a2v[ks] = load_a8(A2, aoff + ks * 32, a2f32);
    }

    {
        const unsigned short* wt = W + (size_t)cb * 16384;
        int4 tmp[8];
#pragma unroll
        for (int q = 0; q < 8; ++q)
            tmp[q] = *(const int4*)(wt + (size_t)(tid + q * 256) * 8);
#pragma unroll
        for (int q = 0; q < 8; ++q)
            *(int4*)(smem + (size_t)(tid + q * 256) * 16) = tmp[q];
        if (W2) {
            const unsigned short* w2t = W2 + (size_t)cb * 16384;
            int4 tm2[8];
#pragma unroll
            for (int q = 0; q < 8; ++q)
                tm2[q] = *(const int4*)(w2t + (size_t)(tid + q * 256) * 8);
#pragma unroll
            for (int q = 0; q < 8; ++q)
                *(int4*)(smem + 32768 + (size_t)(tid + q * 256) * 16) = tm2[q];
        }
    }
    __syncthreads();

    f32x4 acc[8];
#pragma unroll
    for (int c = 0; c < 8; ++c) acc[c] = (f32x4){0.f, 0.f, 0.f, 0.f};

#pragma unroll
    for (int ks = 0; ks < 4; ++ks) {
#pragma unroll
        for (int c = 0; c < 8; ++c) {
            bf16x8 b = *(const bf16x8*)(smem + (size_t)(c * 256 + ks * 64 + lane) * 16);
            acc[c] = __builtin_amdgcn_mfma_f32_16x16x32_bf16(a[ks], b, acc[c], 0, 0, 0);
        }
        if (W2) {
#pragma unroll
            for (int c = 0; c < 8; ++c) {
                bf16x8 b2 = *(const bf16x8*)(smem + 32768 +
                                             (size_t)(c * 256 + ks * 64 + lane) * 16);
                acc[c] = __builtin_amdgcn_mfma_f32_16x16x32_bf16(a2v[ks], b2, acc[c], 0, 0, 0);
            }
        }
    }

#pragma unroll
    for (int c = 0; c < 8; ++c) {
        int col = cb * 128 + c * 16 + m;    // C/D: col = lane&15
        float bias = 0.f;
        if (b1) bias += bf2f(b1[col]);
        if (b2) bias += bf2f(b2[col]);
#pragma unroll
        for (int r = 0; r < 4; ++r) {
            int row = row0 + kh * 4 + r;    // C/D: row = (lane>>4)*4 + reg
            if (row >= n_rows) continue;
            float v = acc[c][r] + bias;
            if (relu_flag && v < 0.f) v = 0.f;
            out[(size_t)row * out_stride + col] = f2bf(v);
        }
    }
}

__global__ __launch_bounds__(256) void gemm_k128(
    const void* __restrict__ A,
    const void* __restrict__ A2,
    const unsigned short* __restrict__ W,
    const unsigned short* __restrict__ W2,
    const unsigned short* __restrict__ b1,
    const unsigned short* __restrict__ b2,
    unsigned short* __restrict__ out,
    int n_rows, int relu_flag, int out_stride,
    const unsigned int* __restrict__ xprobe, int a_sel, int a2_sel)
{
    extern __shared__ __align__(16) char smem[];
    bool f32 = (a_sel | a2_sel) ? detect_fp32(xprobe) : false;
    gemm_body(smem, blockIdx.x, blockIdx.y, A, A2, W, W2, b1, b2, out,
              n_rows, relu_flag, out_stride, a_sel && f32, a2_sel && f32);
}

// K4: fill (blocks [0,HISTB)) || xp1-GEMM (blocks [HISTB, HISTB+782))
__global__ __launch_bounds__(256) void k4_fill_gemm(
    const int* __restrict__ ei, int* __restrict__ cursor, int* __restrict__ elist,
    const void* __restrict__ x,
    const unsigned short* __restrict__ Wp1, const unsigned short* __restrict__ bp1,
    unsigned short* __restrict__ bufA)
{
    extern __shared__ __align__(16) char smem[];
    int bid = blockIdx.x;
    if (bid < HISTB) {
        bool is64 = detect_is64(ei);
        int e = bid * 256 + threadIdx.x;
        if (e >= NE) return;
        int p = atomicAdd(cursor + edst(ei, e, is64), 1);
        elist[p] = esrc(ei, e, is64);
    } else {
        bool f32 = detect_fp32((const unsigned int*)x);
        gemm_body(smem, bid - HISTB, 0, x, nullptr, Wp1, nullptr, bp1, nullptr,
                  bufA, NN, 1, 128, f32, false);
    }
}

// One wave per node: mean over incoming src rows of xp (bf16), write bf16.
__global__ __launch_bounds__(256) void gather_mean_k(
    const int* __restrict__ offs, const int* __restrict__ elist,
    const unsigned short* __restrict__ xp, unsigned short* __restrict__ out)
{
    const int node = blockIdx.x * 4 + (threadIdx.x >> 6);
    const int lane = threadIdx.x & 63;
    if (node >= NN) return;
    const int beg = offs[node], end = offs[node + 1];
    float a0 = 0.f, a1 = 0.f;
    int e = beg;
    for (; e + 4 <= end; e += 4) {
        int s0 = elist[e], s1 = elist[e + 1], s2 = elist[e + 2], s3 = elist[e + 3];
        unsigned int w0 = *(const unsigned int*)(xp + (size_t)s0 * 128 + lane * 2);
        unsigned int w1 = *(const unsigned int*)(xp + (size_t)s1 * 128 + lane * 2);
        unsigned int w2 = *(const unsigned int*)(xp + (size_t)s2 * 128 + lane * 2);
        unsigned int w3 = *(const unsigned int*)(xp + (size_t)s3 * 128 + lane * 2);
        a0 += bf2f((unsigned short)(w0 & 0xFFFFu)) + bf2f((unsigned short)(w1 & 0xFFFFu))
            + bf2f((unsigned short)(w2 & 0xFFFFu)) + bf2f((unsigned short)(w3 & 0xFFFFu));
        a1 += bf2f((unsigned short)(w0 >> 16)) + bf2f((unsigned short)(w1 >> 16))
            + bf2f((unsigned short)(w2 >> 16)) + bf2f((unsigned short)(w3 >> 16));
    }
    for (; e < end; ++e) {
        int s = elist[e];
        unsigned int w = *(const unsigned int*)(xp + (size_t)s * 128 + lane * 2);
        a0 += bf2f((unsigned short)(w & 0xFFFFu));
        a1 += bf2f((unsigned short)(w >> 16));
    }
    int cnt = end - beg;
    float inv = 1.f / (float)(cnt > 1 ? cnt : 1);
    unsigned int o = (unsigned int)f2bf(a0 * inv) | ((unsigned int)f2bf(a1 * inv) << 16);
    *(unsigned int*)(out + (size_t)node * 128 + lane * 2) = o;
}

// LSTM R19: 4 independent waves per 256-thread block, one chunk per wave
// (chunk m = blockIdx.x*4 + waveid). Per-wave body identical to R17/R18:
// depth-3 rotating ring prefetch (use slot t%3, reload with row t+3),
// lane l owns channels (2l,2l+1). No barriers, no LDS -- waves independent.
// Rationale: 64-thread blocks appeared workgroup-slot limited (Occ 12.2%,
// ~3.9 waves/CU resident of 7.8 launched); packing 4 waves/block cuts wg
// slots 4x at identical total work and numerics.
// Chunk 0 burns on row-clamped reads and state is zeroed before the write
// phase. Prefetch overrun for the last chunk reads rows NN..NN+2 (bufA
// region, valid mapped ws memory, values never consumed).
__global__ __launch_bounds__(256) void lstm_chunk_k(
    const unsigned short* __restrict__ pre,
    const unsigned short* __restrict__ Whh,   // [512,3] bf16
    const unsigned short* __restrict__ Whr,   // [3,128] bf16
    void* __restrict__ outv,                  // d_out: hs[150000], hN[3], cN[128]
    const unsigned int* __restrict__ xprobe)
{
    const int m = blockIdx.x * 4 + (threadIdx.x >> 6);
    const int lane = threadIdx.x & 63;
    const bool fp32out = detect_fp32(xprobe);
    float* outf = (float*)outv;
    unsigned short* outb = (unsigned short*)outv;
    const int ch0 = 2 * lane;

    float whh[2][4][3];
#pragma unroll
    for (int j = 0; j < 2; ++j)
#pragma unroll
        for (int g = 0; g < 4; ++g)
#pragma unroll
            for (int k = 0; k < 3; ++k)
                whh[j][g][k] = bf2f(Whh[(g * 128 + ch0 + j) * 3 + k]);
    float whr[2][3];
#pragma unroll
    for (int j = 0; j < 2; ++j)
#pragma unroll
        for (int k = 0; k < 3; ++k)
            whr[j][k] = bf2f(Whr[k * 128 + ch0 + j]);

    const int t0 = m * CLEN;
    const int ts = t0 - BURN;              // m==0: -16, rows clamp to 0

    float ring[3][2][4];
    float h0 = 0.f, h1 = 0.f, h2 = 0.f, c0 = 0.f, c1 = 0.f;
    int T = t0;

// Load row r (clamped at 0 for chunk-0's fake burn) into a [2][4] slot.
#define LOADR(dst, r)                                                          \
    {                                                                          \
        const unsigned short* _pp = pre + ((size_t)((r) > 0 ? (r) : 0) << 9);  \
        _Pragma("unroll")                                                      \
        for (int g = 0; g < 4; ++g) {                                          \
            unsigned int w = *(const unsigned int*)(_pp + g * 128 + ch0);      \
            dst[0][g] = bf2f((unsigned short)(w & 0xFFFFu));                   \
            dst[1][g] = bf2f((unsigned short)(w >> 16));                       \
        }                                                                      \
    }

    LOADR(ring[0], ts)
    LOADR(ring[1], ts + 1)
    LOADR(ring[2], ts + 2)
    int trow = ts + 3;

// One LSTM step: consume ring slot S, then reload S with row trow
// (consumed 3 steps later).
#define STEP(S, DOW)                                                           \
    {                                                                          \
        float gv0[4], gv1[4];                                                  \
        _Pragma("unroll")                                                      \
        for (int g = 0; g < 4; ++g) {                                          \
            gv0[g] = ring[S][0][g] + whh[0][g][0] * h0 + whh[0][g][1] * h1     \
                   + whh[0][g][2] * h2;                                        \
            gv1[g] = ring[S][1][g] + whh[1][g][0] * h0 + whh[1][g][1] * h1     \
                   + whh[1][g][2] * h2;                                        \
        }                                                                      \
        float i0 = sigm(gv0[0]), f0 = sigm(gv0[1]);                            \
        float gg0 = tanh_(gv0[2]), o0 = sigm(gv0[3]);                          \
        float i1 = sigm(gv1[0]), f1 = sigm(gv1[1]);                            \
        float gg1 = tanh_(gv1[2]), o1 = sigm(gv1[3]);                          \
        c0 = f0 * c0 + i0 * gg0;                                               \
        c1 = f1 * c1 + i1 * gg1;                                               \
        float hr0 = o0 * tanh_(c0);                                            \
        float hr1 = o1 * tanh_(c1);                                            \
        float s0 = dpp_sum64(whr[0][0] * hr0 + whr[1][0] * hr1);               \
        float s1 = dpp_sum64(whr[0][1] * hr0 + whr[1][1] * hr1);               \
        float s2 = dpp_sum64(whr[0][2] * hr0 + whr[1][2] * hr1);               \
        h0 = lane63(s0); h1 = lane63(s1); h2 = lane63(s2);                     \
        if (DOW) {                                                             \
            if (lane < 3) {                                                    \
                float v = (lane == 0) ? h0 : ((lane == 1) ? h1 : h2);          \
                size_t idx = (size_t)T * 3 + lane;                             \
                if (fp32out) outf[idx] = v; else outb[idx] = f2bf(v);          \
            }                                                                  \
            T++;                                                               \
        }                                                                      \
        LOADR(ring[S], trow)                                                   \
        trow++;                                                                \
    }

    // Burn-in: steps 0..15 (step t uses slot t%3); all chunks burn; chunk 0
    // burns on clamped row-0 reads, then resets to the exact zero state.
#pragma unroll 1
    for (int i = 0; i < 5; ++i) { STEP(0, 0) STEP(1, 0) STEP(2, 0) }
    STEP(0, 0)

    if (m == 0) { h0 = h1 = h2 = 0.f; c0 = c1 = 0.f; }

    // Write phase: steps 16..40 (slot sequence continues at 16%3 == 1).
    STEP(1, 1) STEP(2, 1)
#pragma unroll 1
    for (int i = 0; i < 7; ++i) { STEP(0, 1) STEP(1, 1) STEP(2, 1) }
    STEP(0, 1) STEP(1, 1)

#undef STEP
#undef LOADR

    if (m == CHUNKS - 1) {
        if (lane < 3) {
            float v = (lane == 0) ? h0 : ((lane == 1) ? h1 : h2);
            if (fp32out) outf[150000 + lane] = v; else outb[150000 + lane] = f2bf(v);
        }
        if (fp32out) {
            outf[150003 + ch0] = c0;
            outf[150003 + ch0 + 1] = c1;
        } else {
            outb[150003 + ch0] = f2bf(c0);
            outb[150003 + ch0 + 1] = f2bf(c1);
        }
    }
}

extern "C" void kernel_launch(void* const* d_in, const int* in_sizes, int n_in,
                              void* d_out, int out_size, void* d_ws, size_t ws_size,
                              hipStream_t stream)
{
    const int* ei = (const int*)d_in[1];
    const unsigned int* xprobe = (const unsigned int*)d_in[0];

    // ---- workspace layout (~64.7 MB) ----
    char* ws = (char*)d_ws;
    const size_t PRE_B  = (size_t)NN * 512 * 2;   // 51.2 MB
    const size_t NODE_B = (size_t)NN * 128 * 2;   // 12.8 MB
    unsigned short* pre  = (unsigned short*)ws;
    unsigned short* bufB = (unsigned short*)ws;                    // alias
    unsigned short* bufC = (unsigned short*)(ws + NODE_B);         // alias
    int* elist  = (int*)(ws + 2 * NODE_B);                         // alias, 2.4MB
    int* offs   = (int*)(ws + 2 * NODE_B + (size_t)NE * 4);        // NN+1 ints
    int* cursor = offs + (NN + 256);
    int* hist   = cursor + (NN + 256);
    int* tsum   = hist + (NN + 256);
    unsigned short* bufA = (unsigned short*)(ws + PRE_B);
    unsigned short* wbuf = (unsigned short*)(ws + PRE_B + NODE_B);

    // bf16 weight copies, element offsets into wbuf (matches cvt_w tables):
    unsigned short* Wp1 = wbuf + 0;      unsigned short* bp1 = wbuf + 16384;
    unsigned short* Wl1 = wbuf + 16512;  unsigned short* bl1 = wbuf + 32896;
    unsigned short* Wr1 = wbuf + 33024;
    unsigned short* Wp2 = wbuf + 49408;  unsigned short* bp2 = wbuf + 65792;
    unsigned short* Wl2 = wbuf + 65920;  unsigned short* bl2 = wbuf + 82304;
    unsigned short* Wr2 = wbuf + 82432;
    unsigned short* Wih = wbuf + 98816;  unsigned short* Whh = wbuf + 164352;
    unsigned short* bih = wbuf + 165888; unsigned short* bhh = wbuf + 166400;
    unsigned short* Whr = wbuf + 166912;

    dim3 b256(256), b1024(1024);
    const size_t LDS1 = 32768, LDS2 = 65536;

    WSrc wsrc;
    {
        const int order[15] = {2,3,4,5,6,7,8,9,10,11,12,13,14,15,16};
        for (int i = 0; i < 15; ++i) wsrc.p[i] = d_in[order[i]];
    }

    hipMemsetAsync(hist, 0, (size_t)NN * 4, stream);

    // K1: hist || weight-convert
    k1_hist_cvtw<<<dim3(HISTB + 3840), b256, 0, stream>>>(ei, hist, wsrc, wbuf, xprobe);
    scanA_k<<<dim3(STILES), b1024, 0, stream>>>(hist, offs, tsum);
    scanC_k<<<dim3(STILES), b1024, 0, stream>>>(offs, cursor, tsum);

    // K4: fill || xp1-GEMM (independent: fill needs CSR, GEMM needs weights)
    k4_fill_gemm<<<dim3(HISTB + 782), b256, LDS1, stream>>>(
        ei, cursor, elist, d_in[0], Wp1, bp1, bufA);

    gather_mean_k<<<dim3(12500), b256, 0, stream>>>(offs, elist, bufA, bufC);
    gemm_k128<<<dim3(782, 1), b256, LDS2, stream>>>(bufC, d_in[0], Wl1, Wr1, bl1, nullptr,
                                                    bufB, NN, 1, 128, xprobe, 0, 1); // h1

    gemm_k128<<<dim3(782, 1), b256, LDS1, stream>>>(bufB, nullptr, Wp2, nullptr, bp2, nullptr,
                                                    bufA, NN, 1, 128, xprobe, 0, 0); // xp2
    gather_mean_k<<<dim3(12500), b256, 0, stream>>>(offs, elist, bufA, bufC);
    gemm_k128<<<dim3(782, 1), b256, LDS2, stream>>>(bufC, bufB, Wl2, Wr2, bl2, nullptr,
                                                    bufA, NN, 0, 128, xprobe, 0, 0); // h2

    // LSTM pre-activations: [N][512] row-major, coalesced writes
    gemm_k128<<<dim3(782, 4), b256, LDS1, stream>>>(bufA, nullptr, Wih, nullptr, bih, bhh,
                                                    pre, NN, 0, 512, xprobe, 0, 0);

    // LSTM: 500 blocks x 256 threads, 4 independent chunks per block (R19)
    lstm_chunk_k<<<dim3(CHUNKS / 4), b256, 0, stream>>>(pre, Whh, Whr, d_out, xprobe);
}

// Round 5
// 331.929 us; speedup vs baseline: 1.1923x; 1.0819x over previous
//
#include <hip/hip_runtime.h>
#include <hip/hip_bf16.h>

// NodeSAGELSTM: 2x SAGEConv(project=True, mean aggr) + ReLU, then LSTM(proj=3).
//
// R20 (post-mortem R19 @ 359.1us: lstm fixed by 4-wave blocks, new top =
// k4_fill_gemm 55-60us with VALUBusy 5%, MfmaUtil 1%, HBM 14% -- pure
// latency/serialization on the fill's atomic chain):
//  - The pipeline paid the 600K-edge atomic pass TWICE: K1's hist atomicAdd
//    (return discarded, hidden by cvtw blocks) and k4's cursor atomicAdd
//    (return needed, exposed: atomic -> vmcnt wait -> dependent scatter store).
//  - R20: K1 stores the atomic return as rank[e] (coalesced 4B). k4's fill
//    becomes elist[offs[d] + rank[e]] = src[e]: no atomic, no dependency,
//    fire-and-forget scatter store. One atomic pass total instead of two.
//  - k4 grid reordered: GEMM blocks first, scatter blocks drain behind.
//  - rank aliases the bufC region (dead before gather_mean overwrites it).
//  - cursor no longer written (scanC slims down).
//  LSTM (R19 shape: 500x256, 4 chunks/block) and all else unchanged.

#define NN 50000
#define NE 600000
#define CHUNKS 2000
#define CLEN 25
#define BURN 16

typedef __attribute__((ext_vector_type(8))) short bf16x8;
typedef __attribute__((ext_vector_type(4))) float f32x4;

__device__ __forceinline__ float bf2f(unsigned short u) {
    union { unsigned int i; float f; } v; v.i = ((unsigned int)u) << 16; return v.f;
}
__device__ __forceinline__ unsigned short f2bf(float f) {
    union { float f; unsigned int i; } v; v.f = f;
    unsigned int x = v.i;
    return (unsigned short)((x + 0x7FFFu + ((x >> 16) & 1u)) >> 16);
}
__device__ __forceinline__ float sigm(float x) { return 1.f / (1.f + __expf(-x)); }
__device__ __forceinline__ float tanh_(float x) {
    float t = __expf(2.f * x);          // saturates cleanly at +-1
    return 1.f - 2.f / (t + 1.f);
}

// Self-detection (uniform, branch-free, L1-cached probes).
__device__ __forceinline__ bool detect_fp32(const unsigned int* __restrict__ xw) {
    int cnt = 0;
#pragma unroll
    for (int i = 0; i < 32; ++i) {
        float av = fabsf(bf2f((unsigned short)(xw[i] & 0xFFFFu)));
        cnt += (av > 1e-6f && av < 1e4f) ? 1 : 0;
    }
    return cnt < 16;
}
__device__ __forceinline__ bool detect_is64(const int* __restrict__ ei) {
    bool z = true;
#pragma unroll
    for (int i = 1; i < 16; i += 2) z = z && (ei[i] == 0);
    return z;
}

// 64-lane sum via DPP (row_shr 1/2/4/8 + row_bcast 15/31); result in lane 63.
__device__ __forceinline__ float dpp_sum64(float x) {
    int v;
    v = __builtin_amdgcn_update_dpp(0, __float_as_int(x), 0x111, 0xf, 0xf, true);
    x += __int_as_float(v);
    v = __builtin_amdgcn_update_dpp(0, __float_as_int(x), 0x112, 0xf, 0xf, true);
    x += __int_as_float(v);
    v = __builtin_amdgcn_update_dpp(0, __float_as_int(x), 0x114, 0xf, 0xf, true);
    x += __int_as_float(v);
    v = __builtin_amdgcn_update_dpp(0, __float_as_int(x), 0x118, 0xf, 0xf, true);
    x += __int_as_float(v);
    v = __builtin_amdgcn_update_dpp(0, __float_as_int(x), 0x142, 0xa, 0xf, true);
    x += __int_as_float(v);
    v = __builtin_amdgcn_update_dpp(0, __float_as_int(x), 0x143, 0xc, 0xf, true);
    x += __int_as_float(v);
    return x;
}
__device__ __forceinline__ float lane63(float x) {
    return __int_as_float(__builtin_amdgcn_readlane(__float_as_int(x), 63));
}

__device__ __forceinline__ int clampn(int v) {
    v = v < 0 ? 0 : v; return v >= NN ? NN - 1 : v;
}
__device__ __forceinline__ int edst(const int* ei, int e, bool is64) {
    return clampn(is64 ? ei[2 * NE + 2 * e] : ei[NE + e]);
}
__device__ __forceinline__ int esrc(const int* ei, int e, bool is64) {
    return clampn(is64 ? ei[2 * e] : ei[e]);
}

// ---- weight conversion (device body; called from fused K1) ----
struct WSrc { const void* p[15]; };
__device__ __forceinline__ void cvt_w_body(
    const WSrc& sp, unsigned short* __restrict__ wbuf, bool f32,
    int seg, int i)
{
    static const int segoff[15] = {0, 16384, 16512, 32896, 33024, 49408, 65792,
                                   65920, 82304, 82432, 98816, 164352, 165888,
                                   166400, 166912};
    static const int segn[15]   = {16384, 128, 16384, 128, 16384, 16384, 128,
                                   16384, 128, 16384, 65536, 1536, 512, 512, 384};
    static const int segmat[15] = {1, 0, 1, 0, 1, 1, 0, 1, 0, 1, 1, 0, 0, 0, 0};
    if (i >= segn[seg]) return;
    float val;
    if (f32) val = ((const float*)sp.p[seg])[i];
    else     val = bf2f(((const unsigned short*)sp.p[seg])[i]);
    int dst = i;
    if (segmat[seg]) {
        int row = i >> 7, kcol = i & 127;
        int tile = row >> 7, r = row & 127;
        int c = r >> 4, m = r & 15;
        int ks = kcol >> 5, kh = (kcol >> 3) & 3, j = kcol & 7;
        dst = (tile << 14) + (((c << 8) + (ks << 6) + (kh << 4) + m) << 3) + j;
    }
    wbuf[segoff[seg] + dst] = f2bf(val);
}

#define HISTB 2344   // ceil(600000/256)

// K1: hist+rank (blocks [0,HISTB)) || weight convert (blocks [HISTB,+3840)).
// rank[e] = arrival index of edge e within its dst bucket (atomic return,
// previously discarded) -- lets the fill pass run atomic-free.
__global__ __launch_bounds__(256) void k1_hist_cvtw(
    const int* __restrict__ ei, int* __restrict__ hist, int* __restrict__ rank,
    WSrc sp, unsigned short* __restrict__ wbuf,
    const unsigned int* __restrict__ xprobe)
{
    int bid = blockIdx.x;
    if (bid < HISTB) {
        bool is64 = detect_is64(ei);
        int e = bid * 256 + threadIdx.x;
        if (e < NE) {
            int p = atomicAdd(hist + edst(ei, e, is64), 1);
            rank[e] = p;
        }
    } else {
        int b2 = bid - HISTB;
        int seg = b2 >> 8;
        int i = (b2 & 255) * 256 + threadIdx.x;
        bool f32 = detect_fp32(xprobe);
        cvt_w_body(sp, wbuf, f32, seg, i);
    }
}

#define STILES 49   // ceil(50000/1024)

__global__ __launch_bounds__(1024) void scanA_k(
    const int* __restrict__ hist, int* __restrict__ offs, int* __restrict__ tsum)
{
    __shared__ int sh[1024];
    int t = threadIdx.x, idx = blockIdx.x * 1024 + t;
    int v = (idx < NN) ? hist[idx] : 0;
    sh[t] = v;
    __syncthreads();
    int acc = v;
    for (int off = 1; off < 1024; off <<= 1) {
        int y = (t >= off) ? sh[t - off] : 0;
        __syncthreads();
        acc += y; sh[t] = acc;
        __syncthreads();
    }
    if (idx < NN) offs[idx] = acc - v;            // exclusive within tile
    if (t == 1023) tsum[blockIdx.x] = acc;        // tile total
}

// scanC': adds per-block base (wave-reduced from tsum). offs[NN] = NE exact.
__global__ __launch_bounds__(1024) void scanC_k(
    int* __restrict__ offs, const int* __restrict__ tsum)
{
    __shared__ int sbase;
    int t = threadIdx.x;
    if (t < 64) {
        int v = (t < STILES && t < (int)blockIdx.x) ? tsum[t] : 0;
#pragma unroll
        for (int off = 32; off > 0; off >>= 1) v += __shfl_xor(v, off, 64);
        if (t == 0) sbase = v;
    }
    __syncthreads();
    int idx = blockIdx.x * 1024 + t;
    if (idx < NN) offs[idx] += sbase;
    if (blockIdx.x == STILES - 1 && t == 0) offs[NN] = NE;
}

// A-fragment load: bf16x8 from bf16 buffer, or inline-convert from fp32 input.
__device__ __forceinline__ bf16x8 load_a8(const void* A, size_t off, bool f32) {
    if (f32) {
        const float* pf = (const float*)A + off;
        f32x4 u0 = *(const f32x4*)pf;
        f32x4 u1 = *(const f32x4*)(pf + 4);
        bf16x8 r;
        r[0] = (short)f2bf(u0[0]); r[1] = (short)f2bf(u0[1]);
        r[2] = (short)f2bf(u0[2]); r[3] = (short)f2bf(u0[3]);
        r[4] = (short)f2bf(u1[0]); r[5] = (short)f2bf(u1[1]);
        r[6] = (short)f2bf(u1[2]); r[7] = (short)f2bf(u1[3]);
        return r;
    }
    return *(const bf16x8*)((const unsigned short*)A + off);
}

// GEMM body (R11 structure): W/W2 in fragment order, staged to LDS (flat int4
// copy); B-fragments via conflict-free contiguous ds_read_b128; A-loads
// hoisted above the staging barrier.
__device__ __forceinline__ void gemm_body(
    char* smem, int bidx, int cb,
    const void* __restrict__ A, const void* __restrict__ A2,
    const unsigned short* __restrict__ W, const unsigned short* __restrict__ W2,
    const unsigned short* __restrict__ b1, const unsigned short* __restrict__ b2,
    unsigned short* __restrict__ out,
    int n_rows, int relu_flag, int out_stride, bool af32, bool a2f32)
{
    const int tid  = threadIdx.x;
    const int lane = tid & 63;
    const int wv   = tid >> 6;
    const int row0 = bidx * 64 + wv * 16;
    const int m    = lane & 15;
    const int kh   = lane >> 4;

    int arow = row0 + m; if (arow >= n_rows) arow = n_rows - 1;
    const size_t aoff = (size_t)arow * 128 + kh * 8;

    bf16x8 a[4], a2v[4];
#pragma unroll
    for (int ks = 0; ks < 4; ++ks) a[ks] = load_a8(A, aoff + ks * 32, af32);
    if (A2) {
#pragma unroll
        for (int ks = 0; ks < 4; ++ks) a2v[ks] = load_a8(A2, aoff + ks * 32, a2f32);
    }

    {
        const unsigned short* wt = W + (size_t)cb * 16384;
        int4 tmp[8];
#pragma unroll
        for (int q = 0; q < 8; ++q)
            tmp[q] = *(const int4*)(wt + (size_t)(tid + q * 256) * 8);
#pragma unroll
        for (int q = 0; q < 8; ++q)
            *(int4*)(smem + (size_t)(tid + q * 256) * 16) = tmp[q];
        if (W2) {
            const unsigned short* w2t = W2 + (size_t)cb * 16384;
            int4 tm2[8];
#pragma unroll
            for (int q = 0; q < 8; ++q)
                tm2[q] = *(const int4*)(w2t + (size_t)(tid + q * 256) * 8);
#pragma unroll
            for (int q = 0; q < 8; ++q)
                *(int4*)(smem + 32768 + (size_t)(tid + q * 256) * 16) = tm2[q];
        }
    }
    __syncthreads();

    f32x4 acc[8];
#pragma unroll
    for (int c = 0; c < 8; ++c) acc[c] = (f32x4){0.f, 0.f, 0.f, 0.f};

#pragma unroll
    for (int ks = 0; ks < 4; ++ks) {
#pragma unroll
        for (int c = 0; c < 8; ++c) {
            bf16x8 b = *(const bf16x8*)(smem + (size_t)(c * 256 + ks * 64 + lane) * 16);
            acc[c] = __builtin_amdgcn_mfma_f32_16x16x32_bf16(a[ks], b, acc[c], 0, 0, 0);
        }
        if (W2) {
#pragma unroll
            for (int c = 0; c < 8; ++c) {
                bf16x8 b2 = *(const bf16x8*)(smem + 32768 +
                                             (size_t)(c * 256 + ks * 64 + lane) * 16);
                acc[c] = __builtin_amdgcn_mfma_f32_16x16x32_bf16(a2v[ks], b2, acc[c], 0, 0, 0);
            }
        }
    }

#pragma unroll
    for (int c = 0; c < 8; ++c) {
        int col = cb * 128 + c * 16 + m;    // C/D: col = lane&15
        float bias = 0.f;
        if (b1) bias += bf2f(b1[col]);
        if (b2) bias += bf2f(b2[col]);
#pragma unroll
        for (int r = 0; r < 4; ++r) {
            int row = row0 + kh * 4 + r;    // C/D: row = (lane>>4)*4 + reg
            if (row >= n_rows) continue;
            float v = acc[c][r] + bias;
            if (relu_flag && v < 0.f) v = 0.f;
            out[(size_t)row * out_stride + col] = f2bf(v);
        }
    }
}

__global__ __launch_bounds__(256) void gemm_k128(
    const void* __restrict__ A,
    const void* __restrict__ A2,
    const unsigned short* __restrict__ W,
    const unsigned short* __restrict__ W2,
    const unsigned short* __restrict__ b1,
    const unsigned short* __restrict__ b2,
    unsigned short* __restrict__ out,
    int n_rows, int relu_flag, int out_stride,
    const unsigned int* __restrict__ xprobe, int a_sel, int a2_sel)
{
    extern __shared__ __align__(16) char smem[];
    bool f32 = (a_sel | a2_sel) ? detect_fp32(xprobe) : false;
    gemm_body(smem, blockIdx.x, blockIdx.y, A, A2, W, W2, b1, b2, out,
              n_rows, relu_flag, out_stride, a_sel && f32, a2_sel && f32);
}

// K4: xp1-GEMM (blocks [0,782)) || atomic-free fill (blocks [782, 782+HISTB)).
// GEMM blocks first so compute-dense work isn't queued behind the scatter.
// Fill: elist[offs[d] + rank[e]] = src[e] -- no atomic, store fire-and-forget.
__global__ __launch_bounds__(256) void k4_fill_gemm(
    const int* __restrict__ ei,
    const int* __restrict__ offs, const int* __restrict__ rank,
    int* __restrict__ elist,
    const void* __restrict__ x,
    const unsigned short* __restrict__ Wp1, const unsigned short* __restrict__ bp1,
    unsigned short* __restrict__ bufA)
{
    extern __shared__ __align__(16) char smem[];
    int bid = blockIdx.x;
    if (bid < 782) {
        bool f32 = detect_fp32((const unsigned int*)x);
        gemm_body(smem, bid, 0, x, nullptr, Wp1, nullptr, bp1, nullptr,
                  bufA, NN, 1, 128, f32, false);
    } else {
        bool is64 = detect_is64(ei);
        int e = (bid - 782) * 256 + threadIdx.x;
        if (e >= NE) return;
        int d = edst(ei, e, is64);
        elist[offs[d] + rank[e]] = esrc(ei, e, is64);
    }
}

// One wave per node: mean over incoming src rows of xp (bf16), write bf16.
__global__ __launch_bounds__(256) void gather_mean_k(
    const int* __restrict__ offs, const int* __restrict__ elist,
    const unsigned short* __restrict__ xp, unsigned short* __restrict__ out)
{
    const int node = blockIdx.x * 4 + (threadIdx.x >> 6);
    const int lane = threadIdx.x & 63;
    if (node >= NN) return;
    const int beg = offs[node], end = offs[node + 1];
    float a0 = 0.f, a1 = 0.f;
    int e = beg;
    for (; e + 4 <= end; e += 4) {
        int s0 = elist[e], s1 = elist[e + 1], s2 = elist[e + 2], s3 = elist[e + 3];
        unsigned int w0 = *(const unsigned int*)(xp + (size_t)s0 * 128 + lane * 2);
        unsigned int w1 = *(const unsigned int*)(xp + (size_t)s1 * 128 + lane * 2);
        unsigned int w2 = *(const unsigned int*)(xp + (size_t)s2 * 128 + lane * 2);
        unsigned int w3 = *(const unsigned int*)(xp + (size_t)s3 * 128 + lane * 2);
        a0 += bf2f((unsigned short)(w0 & 0xFFFFu)) + bf2f((unsigned short)(w1 & 0xFFFFu))
            + bf2f((unsigned short)(w2 & 0xFFFFu)) + bf2f((unsigned short)(w3 & 0xFFFFu));
        a1 += bf2f((unsigned short)(w0 >> 16)) + bf2f((unsigned short)(w1 >> 16))
            + bf2f((unsigned short)(w2 >> 16)) + bf2f((unsigned short)(w3 >> 16));
    }
    for (; e < end; ++e) {
        int s = elist[e];
        unsigned int w = *(const unsigned int*)(xp + (size_t)s * 128 + lane * 2);
        a0 += bf2f((unsigned short)(w & 0xFFFFu));
        a1 += bf2f((unsigned short)(w >> 16));
    }
    int cnt = end - beg;
    float inv = 1.f / (float)(cnt > 1 ? cnt : 1);
    unsigned int o = (unsigned int)f2bf(a0 * inv) | ((unsigned int)f2bf(a1 * inv) << 16);
    *(unsigned int*)(out + (size_t)node * 128 + lane * 2) = o;
}

// LSTM R19 (kept): 4 independent waves per 256-thread block, one chunk per
// wave (chunk m = blockIdx.x*4 + waveid); depth-3 rotating ring prefetch;
// lane l owns channels (2l,2l+1). Chunk 0 burns on row-clamped reads and
// state is zeroed before the write phase. Prefetch overrun for the last
// chunk reads rows NN..NN+2 (bufA region, valid mapped ws, unused).
__global__ __launch_bounds__(256) void lstm_chunk_k(
    const unsigned short* __restrict__ pre,
    const unsigned short* __restrict__ Whh,   // [512,3] bf16
    const unsigned short* __restrict__ Whr,   // [3,128] bf16
    void* __restrict__ outv,                  // d_out: hs[150000], hN[3], cN[128]
    const unsigned int* __restrict__ xprobe)
{
    const int m = blockIdx.x * 4 + (threadIdx.x >> 6);
    const int lane = threadIdx.x & 63;
    const bool fp32out = detect_fp32(xprobe);
    float* outf = (float*)outv;
    unsigned short* outb = (unsigned short*)outv;
    const int ch0 = 2 * lane;

    float whh[2][4][3];
#pragma unroll
    for (int j = 0; j < 2; ++j)
#pragma unroll
        for (int g = 0; g < 4; ++g)
#pragma unroll
            for (int k = 0; k < 3; ++k)
                whh[j][g][k] = bf2f(Whh[(g * 128 + ch0 + j) * 3 + k]);
    float whr[2][3];
#pragma unroll
    for (int j = 0; j < 2; ++j)
#pragma unroll
        for (int k = 0; k < 3; ++k)
            whr[j][k] = bf2f(Whr[k * 128 + ch0 + j]);

    const int t0 = m * CLEN;
    const int ts = t0 - BURN;              // m==0: -16, rows clamp to 0

    float ring[3][2][4];
    float h0 = 0.f, h1 = 0.f, h2 = 0.f, c0 = 0.f, c1 = 0.f;
    int T = t0;

// Load row r (clamped at 0 for chunk-0's fake burn) into a [2][4] slot.
#define LOADR(dst, r)                                                          \
    {                                                                          \
        const unsigned short* _pp = pre + ((size_t)((r) > 0 ? (r) : 0) << 9);  \
        _Pragma("unroll")                                                      \
        for (int g = 0; g < 4; ++g) {                                          \
            unsigned int w = *(const unsigned int*)(_pp + g * 128 + ch0);      \
            dst[0][g] = bf2f((unsigned short)(w & 0xFFFFu));                   \
            dst[1][g] = bf2f((unsigned short)(w >> 16));                       \
        }                                                                      \
    }

    LOADR(ring[0], ts)
    LOADR(ring[1], ts + 1)
    LOADR(ring[2], ts + 2)
    int trow = ts + 3;

// One LSTM step: consume ring slot S, then reload S with row trow
// (consumed 3 steps later).
#define STEP(S, DOW)                                                           \
    {                                                                          \
        float gv0[4], gv1[4];                                                  \
        _Pragma("unroll")                                                      \
        for (int g = 0; g < 4; ++g) {                                          \
            gv0[g] = ring[S][0][g] + whh[0][g][0] * h0 + whh[0][g][1] * h1     \
                   + whh[0][g][2] * h2;                                        \
            gv1[g] = ring[S][1][g] + whh[1][g][0] * h0 + whh[1][g][1] * h1     \
                   + whh[1][g][2] * h2;                                        \
        }                                                                      \
        float i0 = sigm(gv0[0]), f0 = sigm(gv0[1]);                            \
        float gg0 = tanh_(gv0[2]), o0 = sigm(gv0[3]);                          \
        float i1 = sigm(gv1[0]), f1 = sigm(gv1[1]);                            \
        float gg1 = tanh_(gv1[2]), o1 = sigm(gv1[3]);                          \
        c0 = f0 * c0 + i0 * gg0;                                               \
        c1 = f1 * c1 + i1 * gg1;                                               \
        float hr0 = o0 * tanh_(c0);                                            \
        float hr1 = o1 * tanh_(c1);                                            \
        float s0 = dpp_sum64(whr[0][0] * hr0 + whr[1][0] * hr1);               \
        float s1 = dpp_sum64(whr[0][1] * hr0 + whr[1][1] * hr1);               \
        float s2 = dpp_sum64(whr[0][2] * hr0 + whr[1][2] * hr1);               \
        h0 = lane63(s0); h1 = lane63(s1); h2 = lane63(s2);                     \
        if (DOW) {                                                             \
            if (lane < 3) {                                                    \
                float v = (lane == 0) ? h0 : ((lane == 1) ? h1 : h2);          \
                size_t idx = (size_t)T * 3 + lane;                             \
                if (fp32out) outf[idx] = v; else outb[idx] = f2bf(v);          \
            }                                                                  \
            T++;                                                               \
        }                                                                      \
        LOADR(ring[S], trow)                                                   \
        trow++;                                                                \
    }

    // Burn-in: steps 0..15 (step t uses slot t%3); all chunks burn; chunk 0
    // burns on clamped row-0 reads, then resets to the exact zero state.
#pragma unroll 1
    for (int i = 0; i < 5; ++i) { STEP(0, 0) STEP(1, 0) STEP(2, 0) }
    STEP(0, 0)

    if (m == 0) { h0 = h1 = h2 = 0.f; c0 = c1 = 0.f; }

    // Write phase: steps 16..40 (slot sequence continues at 16%3 == 1).
    STEP(1, 1) STEP(2, 1)
#pragma unroll 1
    for (int i = 0; i < 7; ++i) { STEP(0, 1) STEP(1, 1) STEP(2, 1) }
    STEP(0, 1) STEP(1, 1)

#undef STEP
#undef LOADR

    if (m == CHUNKS - 1) {
        if (lane < 3) {
            float v = (lane == 0) ? h0 : ((lane == 1) ? h1 : h2);
            if (fp32out) outf[150000 + lane] = v; else outb[150000 + lane] = f2bf(v);
        }
        if (fp32out) {
            outf[150003 + ch0] = c0;
            outf[150003 + ch0 + 1] = c1;
        } else {
            outb[150003 + ch0] = f2bf(c0);
            outb[150003 + ch0 + 1] = f2bf(c1);
        }
    }
}

extern "C" void kernel_launch(void* const* d_in, const int* in_sizes, int n_in,
                              void* d_out, int out_size, void* d_ws, size_t ws_size,
                              hipStream_t stream)
{
    const int* ei = (const int*)d_in[1];
    const unsigned int* xprobe = (const unsigned int*)d_in[0];

    // ---- workspace layout (~64.7 MB) ----
    char* ws = (char*)d_ws;
    const size_t PRE_B  = (size_t)NN * 512 * 2;   // 51.2 MB
    const size_t NODE_B = (size_t)NN * 128 * 2;   // 12.8 MB
    unsigned short* pre  = (unsigned short*)ws;
    unsigned short* bufB = (unsigned short*)ws;                    // alias
    unsigned short* bufC = (unsigned short*)(ws + NODE_B);         // alias
    // rank aliases bufC's first 2.4MB: written by K1, consumed by k4's fill,
    // dead before gather_mean overwrites bufC.
    int* rank   = (int*)(ws + NODE_B);
    int* elist  = (int*)(ws + 2 * NODE_B);                         // alias, 2.4MB
    int* offs   = (int*)(ws + 2 * NODE_B + (size_t)NE * 4);        // NN+1 ints
    int* cursor = offs + (NN + 256);                               // (unused)
    int* hist   = cursor + (NN + 256);
    int* tsum   = hist + (NN + 256);
    unsigned short* bufA = (unsigned short*)(ws + PRE_B);
    unsigned short* wbuf = (unsigned short*)(ws + PRE_B + NODE_B);

    // bf16 weight copies, element offsets into wbuf (matches cvt_w tables):
    unsigned short* Wp1 = wbuf + 0;      unsigned short* bp1 = wbuf + 16384;
    unsigned short* Wl1 = wbuf + 16512;  unsigned short* bl1 = wbuf + 32896;
    unsigned short* Wr1 = wbuf + 33024;
    unsigned short* Wp2 = wbuf + 49408;  unsigned short* bp2 = wbuf + 65792;
    unsigned short* Wl2 = wbuf + 65920;  unsigned short* bl2 = wbuf + 82304;
    unsigned short* Wr2 = wbuf + 82432;
    unsigned short* Wih = wbuf + 98816;  unsigned short* Whh = wbuf + 164352;
    unsigned short* bih = wbuf + 165888; unsigned short* bhh = wbuf + 166400;
    unsigned short* Whr = wbuf + 166912;

    dim3 b256(256), b1024(1024);
    const size_t LDS1 = 32768, LDS2 = 65536;

    WSrc wsrc;
    {
        const int order[15] = {2,3,4,5,6,7,8,9,10,11,12,13,14,15,16};
        for (int i = 0; i < 15; ++i) wsrc.p[i] = d_in[order[i]];
    }

    hipMemsetAsync(hist, 0, (size_t)NN * 4, stream);

    // K1: hist+rank || weight-convert
    k1_hist_cvtw<<<dim3(HISTB + 3840), b256, 0, stream>>>(ei, hist, rank, wsrc,
                                                          wbuf, xprobe);
    scanA_k<<<dim3(STILES), b1024, 0, stream>>>(hist, offs, tsum);
    scanC_k<<<dim3(STILES), b1024, 0, stream>>>(offs, tsum);

    // K4: xp1-GEMM first || atomic-free fill behind
    k4_fill_gemm<<<dim3(782 + HISTB), b256, LDS1, stream>>>(
        ei, offs, rank, elist, d_in[0], Wp1, bp1, bufA);

    gather_mean_k<<<dim3(12500), b256, 0, stream>>>(offs, elist, bufA, bufC);
    gemm_k128<<<dim3(782, 1), b256, LDS2, stream>>>(bufC, d_in[0], Wl1, Wr1, bl1, nullptr,
                                                    bufB, NN, 1, 128, xprobe, 0, 1); // h1

    gemm_k128<<<dim3(782, 1), b256, LDS1, stream>>>(bufB, nullptr, Wp2, nullptr, bp2, nullptr,
                                                    bufA, NN, 1, 128, xprobe, 0, 0); // xp2
    gather_mean_k<<<dim3(12500), b256, 0, stream>>>(offs, elist, bufA, bufC);
    gemm_k128<<<dim3(782, 1), b256, LDS2, stream>>>(bufC, bufB, Wl2, Wr2, bl2, nullptr,
                                                    bufA, NN, 0, 128, xprobe, 0, 0); // h2

    // LSTM pre-activations: [N][512] row-major, coalesced writes
    gemm_k128<<<dim3(782, 4), b256, LDS1, stream>>>(bufA, nullptr, Wih, nullptr, bih, bhh,
                                                    pre, NN, 0, 512, xprobe, 0, 0);

    // LSTM: 500 blocks x 256 threads, 4 independent chunks per block (R19)
    lstm_chunk_k<<<dim3(CHUNKS / 4), b256, 0, stream>>>(pre, Whh, Whr, d_out, xprobe);
}